// Round 1
// baseline (906.831 us; speedup 1.0000x reference)
//
#include <hip/hip_runtime.h>

#define C_DIM 256
#define N_EMB 1024
#define HW    4096          // 64*64
#define QN    16777216      // quantize element count
#define NPIX  65536

// -------- kernel 1: ||e||^2 per code --------
__global__ __launch_bounds__(256) void enorm_kernel(const float* __restrict__ embed,
                                                    float* __restrict__ enorm) {
    int e = blockIdx.x * 256 + threadIdx.x;
    float s = 0.f;
    #pragma unroll 8
    for (int c = 0; c < C_DIM; ++c) {
        float v = embed[c * N_EMB + e];
        s = fmaf(v, v, s);
    }
    enorm[e] = s;
}

// -------- kernel 2: main VQ --------
// block = 256 threads, 64 pixels (one h-row of one batch image)
// thread tile: 4 pixels x 8 codes; embed streamed in [32k][128e] LDS chunks
__global__ __launch_bounds__(256) void vq_main(
    const float* __restrict__ x, const float* __restrict__ embed,
    const float* __restrict__ enorm, float* __restrict__ out,
    float* __restrict__ diff_partial)
{
    __shared__ float xs[C_DIM][64];   // 64 KB, [c][pixel]
    __shared__ float es[32 * 128];    // 16 KB, [k][e]; reused for reductions

    const int tid = threadIdx.x;
    const int bid = blockIdx.x;       // 0..1023
    const int b = bid >> 6;
    const int h = bid & 63;
    const float* xb = x + (size_t)(b * C_DIM) * HW + h * 64;

    // stage x tile: coalesced (64 consecutive w per c-row)
    for (int i = tid; i < C_DIM * 64; i += 256) {
        ((float*)xs)[i] = xb[(i >> 6) * HW + (i & 63)];
    }
    __syncthreads();

    const int tp = tid & 15;   // pixel group: pixels 4*tp .. 4*tp+3
    const int te = tid >> 4;   // code group : codes te*8 .. te*8+7 (within 128-chunk)

    // ||x||^2 for my 4 pixels
    float xn[4];
    #pragma unroll
    for (int pi = 0; pi < 4; ++pi) {
        int p = tp * 4 + pi;
        float s = 0.f;
        for (int c = 0; c < C_DIM; ++c) s = fmaf(xs[c][p], xs[c][p], s);
        xn[pi] = s;
    }

    float bestd[4];
    int   besti[4];
    #pragma unroll
    for (int pi = 0; pi < 4; ++pi) { bestd[pi] = 3.0e38f; besti[pi] = 0; }

    for (int ec = 0; ec < 8; ++ec) {           // 8 chunks of 128 codes
        float acc[4][8];
        #pragma unroll
        for (int pi = 0; pi < 4; ++pi)
            #pragma unroll
            for (int j = 0; j < 8; ++j) acc[pi][j] = 0.f;

        for (int kc = 0; kc < 8; ++kc) {       // 8 chunks of 32 k
            __syncthreads();                   // prior readers of es done
            for (int i = tid; i < 32 * 128; i += 256) {
                int k = i >> 7, e = i & 127;
                es[i] = embed[(size_t)(kc * 32 + k) * N_EMB + ec * 128 + e];
            }
            __syncthreads();
            #pragma unroll
            for (int k = 0; k < 32; ++k) {
                float4 xv = *(const float4*)&xs[kc * 32 + k][tp * 4];
                float ev[8];
                *(float4*)&ev[0] = *(const float4*)&es[k * 128 + te * 8];
                *(float4*)&ev[4] = *(const float4*)&es[k * 128 + te * 8 + 4];
                #pragma unroll
                for (int pi = 0; pi < 4; ++pi) {
                    float xvv = (&xv.x)[pi];
                    #pragma unroll
                    for (int j = 0; j < 8; ++j)
                        acc[pi][j] = fmaf(xvv, ev[j], acc[pi][j]);
                }
            }
        }
        // fold this chunk into running argmin (codes ascend within thread -> strict <)
        #pragma unroll
        for (int pi = 0; pi < 4; ++pi) {
            #pragma unroll
            for (int j = 0; j < 8; ++j) {
                int e = ec * 128 + te * 8 + j;
                float d = (xn[pi] - 2.0f * acc[pi][j]) + enorm[e];
                if (d < bestd[pi]) { bestd[pi] = d; besti[pi] = e; }
            }
        }
    }

    // cross-group argmin reduction (reuse es region)
    float* redD = es;                 // 1024 floats
    int*   redI = (int*)(es + 1024);  // 1024 ints
    int*   best = (int*)(es + 2048);  // 64 ints
    float* wsum = es + 3072;          // 4 floats

    __syncthreads();                  // all done reading es
    #pragma unroll
    for (int pi = 0; pi < 4; ++pi) {
        int p = tp * 4 + pi;
        redD[te * 64 + p] = bestd[pi];
        redI[te * 64 + p] = besti[pi];
    }
    __syncthreads();
    if (tid < 64) {
        int p = tid;
        float bd = redD[p]; int bi = redI[p];
        #pragma unroll
        for (int g = 1; g < 16; ++g) {
            float d = redD[g * 64 + p]; int i2 = redI[g * 64 + p];
            if (d < bd || (d == bd && i2 < bi)) { bd = d; bi = i2; }
        }
        best[p] = bi;
        out[(size_t)QN + 1 + (size_t)bid * 64 + p] = (float)bi;  // embed_ind as float
    }
    __syncthreads();

    // quantize write + diff partial
    float local = 0.f;
    for (int i = tid; i < C_DIM * 64; i += 256) {
        int c = i >> 6, w = i & 63;
        int e = best[w];
        float q = embed[c * N_EMB + e];
        out[(size_t)(b * C_DIM + c) * HW + h * 64 + w] = q;
        float dv = q - xs[c][w];
        local = fmaf(dv, dv, local);
    }
    #pragma unroll
    for (int off = 32; off > 0; off >>= 1) local += __shfl_down(local, off);
    if ((tid & 63) == 0) wsum[tid >> 6] = local;
    __syncthreads();
    if (tid == 0) diff_partial[bid] = wsum[0] + wsum[1] + wsum[2] + wsum[3];
}

// -------- kernel 3: finalize diff in f64 --------
__global__ __launch_bounds__(256) void finalize_kernel(const float* __restrict__ part,
                                                       float* __restrict__ out) {
    __shared__ double sd[256];
    double s = 0.0;
    for (int i = threadIdx.x; i < 1024; i += 256) s += (double)part[i];
    sd[threadIdx.x] = s;
    __syncthreads();
    for (int st = 128; st > 0; st >>= 1) {
        if (threadIdx.x < st) sd[threadIdx.x] += sd[threadIdx.x + st];
        __syncthreads();
    }
    if (threadIdx.x == 0) out[QN] = (float)(sd[0] / 16777216.0);
}

extern "C" void kernel_launch(void* const* d_in, const int* in_sizes, int n_in,
                              void* d_out, int out_size, void* d_ws, size_t ws_size,
                              hipStream_t stream) {
    const float* x     = (const float*)d_in[0];
    const float* embed = (const float*)d_in[1];
    float* out   = (float*)d_out;
    float* enorm = (float*)d_ws;        // 1024 f32
    float* part  = enorm + 1024;        // 1024 f32

    enorm_kernel<<<4, 256, 0, stream>>>(embed, enorm);
    vq_main<<<1024, 256, 0, stream>>>(x, embed, enorm, out, part);
    finalize_kernel<<<1, 256, 0, stream>>>(part, out);
}

// Round 4
// 337.591 us; speedup vs baseline: 2.6862x; 2.6862x over previous
//
#include <hip/hip_runtime.h>
#include <float.h>

#define C_DIM 256
#define N_EMB 1024
#define HW    4096          // 64*64
#define QN    16777216      // quantize element count
#define NPIX  65536
#define TAU   4.0e-3f

typedef __attribute__((ext_vector_type(8))) short short8;
typedef __attribute__((ext_vector_type(4))) float f32x4;
typedef unsigned long long u64;
typedef unsigned int u32;
typedef unsigned short u16;

__device__ __forceinline__ u16 f2bf(float f) {
    u32 u = __float_as_uint(f);
    return (u16)((u + 0x7FFF + ((u >> 16) & 1)) >> 16);   // RN-even, inputs finite
}
__device__ __forceinline__ float bf2f(u16 h) { return __uint_as_float(((u32)h) << 16); }
__device__ __forceinline__ u64 pack4(u16 a, u16 b, u16 c, u16 d) {
    return (u64)a | ((u64)b << 16) | ((u64)c << 32) | ((u64)d << 48);
}

#define GL2LDS(gp, lp) __builtin_amdgcn_global_load_lds(                         \
    (const __attribute__((address_space(1))) u32*)(gp),                          \
    (__attribute__((address_space(3))) u32*)(lp), 16, 0, 0)

// -------- kernel: ||e||^2 per code --------
__global__ __launch_bounds__(256) void enorm_kernel(const float* __restrict__ embed,
                                                    float* __restrict__ enorm) {
    int e = blockIdx.x * 256 + threadIdx.x;
    float s = 0.f;
    #pragma unroll 8
    for (int c = 0; c < C_DIM; ++c) {
        float v = embed[c * N_EMB + e];
        s = fmaf(v, v, s);
    }
    enorm[e] = s;
}

// -------- prep A': x -> packed swizzled bf16 hi|lo tiles --------
// Ap layout: [mb 512][kc 8][m 128][64 shorts: slots swizzled (slot ^ (m&7))]
// split-K fragment: slot g shorts 0..3 = k (=channel-kc*32) g*4..+3, shorts 4..7 = 16+g*4..+3
__global__ __launch_bounds__(256) void prep_a(const float* __restrict__ x,
                                              short* __restrict__ Ap) {
    int item = blockIdx.x * 256 + threadIdx.x;   // cg*65536 + pix
    int pix = item & 65535;
    int cg  = item >> 16;                        // 0..63, 4 channels each
    int b = pix >> 12, hw = pix & 4095;
    const float* xp = x + (((size_t)(b * C_DIM + cg * 4)) << 12) + hw;
    float v0 = xp[0], v1 = xp[4096], v2 = xp[8192], v3 = xp[12288];
    u16 h0 = f2bf(v0), h1 = f2bf(v1), h2 = f2bf(v2), h3 = f2bf(v3);
    u16 l0 = f2bf(v0 - bf2f(h0)), l1 = f2bf(v1 - bf2f(h1));
    u16 l2 = f2bf(v2 - bf2f(h2)), l3 = f2bf(v3 - bf2f(h3));
    int m = pix & 127, mb = pix >> 7;
    int kc = cg >> 3, cg3 = cg & 7;
    int s = cg3 & 3;
    int half = (cg3 >> 2) << 2;
    size_t row = (((size_t)(mb * 8 + kc)) * 128 + m) * 64;
    int khi = ((s ^ (m & 7)) << 3) + half;
    int klo = (((s + 4) ^ (m & 7)) << 3) + half;
    *(u64*)(Ap + row + khi) = pack4(h0, h1, h2, h3);
    *(u64*)(Ap + row + klo) = pack4(l0, l1, l2, l3);
}

// -------- prep B': embed -> packed swizzled bf16 hi|lo tiles --------
__global__ __launch_bounds__(256) void prep_b(const float* __restrict__ embed,
                                              short* __restrict__ Bp) {
    int item = blockIdx.x * 256 + threadIdx.x;   // cg*1024 + e
    int e  = item & 1023;
    int cg = item >> 10;                         // 0..63
    const float* ep = embed + (size_t)(cg * 4) * N_EMB + e;
    float v0 = ep[0], v1 = ep[1024], v2 = ep[2048], v3 = ep[3072];
    u16 h0 = f2bf(v0), h1 = f2bf(v1), h2 = f2bf(v2), h3 = f2bf(v3);
    u16 l0 = f2bf(v0 - bf2f(h0)), l1 = f2bf(v1 - bf2f(h1));
    u16 l2 = f2bf(v2 - bf2f(h2)), l3 = f2bf(v3 - bf2f(h3));
    int eb = e & 127, nb = e >> 7;
    int kc = cg >> 3, cg3 = cg & 7;
    int s = cg3 & 3;
    int half = (cg3 >> 2) << 2;
    size_t row = (((size_t)(nb * 8 + kc)) * 128 + eb) * 64;
    int khi = ((s ^ (eb & 7)) << 3) + half;
    int klo = (((s + 4) ^ (eb & 7)) << 3) + half;
    *(u64*)(Bp + row + khi) = pack4(h0, h1, h2, h3);
    *(u64*)(Bp + row + klo) = pack4(l0, l1, l2, l3);
}

// -------- main MFMA distance GEMM + per-(nb,wn)-halftile (best,second,idx) --------
__global__ __launch_bounds__(256) void vq_gemm(
    const short* __restrict__ Ap, const short* __restrict__ Bp,
    const float* __restrict__ enorm,
    float* __restrict__ pB, float* __restrict__ pS, int* __restrict__ pI)
{
    __shared__ __align__(1024) short As[8192];   // [m 128][64]
    __shared__ __align__(1024) short Bs[8192];   // [e 128][64]

    const int tid  = threadIdx.x;
    const int bid  = blockIdx.x;
    const int mb   = bid >> 3;        // 0..511
    const int nb   = bid & 7;         // 0..7
    const int wave = tid >> 6;
    const int lane = tid & 63;
    const int wm   = wave & 1;        // row-group of wave (64 rows)
    const int wn   = wave >> 1;       // col-group of wave (64 cols)
    const int col  = lane & 15;
    const int g    = lane >> 4;       // 0..3

    const short* Abase = Ap + (size_t)mb * 65536;
    const short* Bbase = Bp + (size_t)nb * 65536;

    float en[4];
    #pragma unroll
    for (int ni = 0; ni < 4; ++ni)
        en[ni] = enorm[nb * 128 + wn * 64 + ni * 16 + col];

    f32x4 acc[4][4];
    #pragma unroll
    for (int mi = 0; mi < 4; ++mi)
        #pragma unroll
        for (int ni = 0; ni < 4; ++ni)
            acc[mi][ni] = (f32x4)0.0f;

    for (int kc = 0; kc < 8; ++kc) {
        __syncthreads();   // prior chunk's readers done
        {
            const short* ga = Abase + kc * 8192;
            const short* gb = Bbase + kc * 8192;
            #pragma unroll
            for (int i = 0; i < 4; ++i) {
                int off = (i * 4 + wave) * 512 + lane * 8;   // shorts
                GL2LDS(ga + off, &As[off]);
                GL2LDS(gb + off, &Bs[off]);
            }
        }
        __syncthreads();   // drains vmcnt(0)

        short8 ahi[4], alo[4], bhi[4], blo[4];
        #pragma unroll
        for (int mi = 0; mi < 4; ++mi) {
            int r = wm * 64 + mi * 16 + col;
            int base = r * 64;
            ahi[mi] = *(const short8*)&As[base + ((g ^ (r & 7)) << 3)];
            alo[mi] = *(const short8*)&As[base + (((g + 4) ^ (r & 7)) << 3)];
        }
        #pragma unroll
        for (int ni = 0; ni < 4; ++ni) {
            int r = wn * 64 + ni * 16 + col;
            int base = r * 64;
            bhi[ni] = *(const short8*)&Bs[base + ((g ^ (r & 7)) << 3)];
            blo[ni] = *(const short8*)&Bs[base + (((g + 4) ^ (r & 7)) << 3)];
        }
        #pragma unroll
        for (int mi = 0; mi < 4; ++mi)
            #pragma unroll
            for (int ni = 0; ni < 4; ++ni) {
                acc[mi][ni] = __builtin_amdgcn_mfma_f32_16x16x32_bf16(ahi[mi], bhi[ni], acc[mi][ni], 0, 0, 0);
                acc[mi][ni] = __builtin_amdgcn_mfma_f32_16x16x32_bf16(ahi[mi], blo[ni], acc[mi][ni], 0, 0, 0);
                acc[mi][ni] = __builtin_amdgcn_mfma_f32_16x16x32_bf16(alo[mi], bhi[ni], acc[mi][ni], 0, 0, 0);
            }
    }

    // epilogue: per-row (best, second, idx) over this wave's 64 codes
    #pragma unroll
    for (int mi = 0; mi < 4; ++mi) {
        #pragma unroll
        for (int reg = 0; reg < 4; ++reg) {
            float bd = FLT_MAX, sd = FLT_MAX;
            int bi = 0x7fffffff;
            #pragma unroll
            for (int ni = 0; ni < 4; ++ni) {
                float d = en[ni] - 2.0f * acc[mi][ni][reg];
                int c = nb * 128 + wn * 64 + ni * 16 + col;
                if (d < bd) { sd = bd; bd = d; bi = c; }
                else        { sd = fminf(sd, d); }
            }
            #pragma unroll
            for (int mask = 1; mask < 16; mask <<= 1) {
                float ob = __shfl_xor(bd, mask);
                float os = __shfl_xor(sd, mask);
                int   oi = __shfl_xor(bi, mask);
                if (ob < bd || (ob == bd && oi < bi)) { sd = fminf(bd, os); bd = ob; bi = oi; }
                else                                  { sd = fminf(sd, ob); }
            }
            if (col == 0) {
                int pixel = mb * 128 + wm * 64 + mi * 16 + g * 4 + reg;
                size_t o = (size_t)pixel * 16 + nb * 2 + wn;   // unique per (pixel, nb, wn)
                pB[o] = bd; pS[o] = sd; pI[o] = bi;
            }
        }
    }
}

// -------- reduce over 16 half-tiles; flag ambiguous pixels --------
__global__ __launch_bounds__(256) void vq_reduce(
    const float* __restrict__ pB, const float* __restrict__ pS, const int* __restrict__ pI,
    int* __restrict__ ind, int* __restrict__ list, int* __restrict__ cnt)
{
    int p = blockIdx.x * 256 + threadIdx.x;
    size_t o = (size_t)p * 16;
    float bd = pB[o], sd = pS[o];
    int bi = pI[o];
    #pragma unroll
    for (int t = 1; t < 16; ++t) {
        float ob = pB[o + t], os = pS[o + t];
        int   oi = pI[o + t];
        if (ob < bd || (ob == bd && oi < bi)) { sd = fminf(bd, os); bd = ob; bi = oi; }
        else                                  { sd = fminf(sd, ob); }
    }
    ind[p] = bi;
    if (sd - bd < TAU) {
        int pos = atomicAdd(cnt, 1);
        list[pos] = p;
    }
}

// -------- exact f32 re-check for ambiguous pixels (round-1 numerics) --------
__global__ __launch_bounds__(256) void vq_fixup(
    const float* __restrict__ x, const float* __restrict__ embed,
    const float* __restrict__ enorm, const int* __restrict__ list,
    const int* __restrict__ cnt, int* __restrict__ ind)
{
    __shared__ float xr[256];
    __shared__ float xnsh;
    __shared__ float rD[256];
    __shared__ int   rI[256];
    const int tid = threadIdx.x;
    const int nfix = cnt[0];

    for (int j = blockIdx.x; j < nfix; j += gridDim.x) {
        int p = list[j];
        int b = p >> 12, hw = p & 4095;
        xr[tid] = x[(((size_t)(b * C_DIM + tid)) << 12) + hw];
        __syncthreads();
        if (tid == 0) {
            float s = 0.f;
            for (int c = 0; c < C_DIM; ++c) s = fmaf(xr[c], xr[c], s);
            xnsh = s;
        }
        __syncthreads();
        float xn = xnsh;
        float best = FLT_MAX; int bi = 0;
        #pragma unroll
        for (int j4 = 0; j4 < 4; ++j4) {
            int e = j4 * 256 + tid;
            float acc = 0.f;
            for (int c = 0; c < C_DIM; ++c) acc = fmaf(xr[c], embed[c * N_EMB + e], acc);
            float d = (xn - 2.0f * acc) + enorm[e];
            if (d < best) { best = d; bi = e; }
        }
        rD[tid] = best; rI[tid] = bi;
        __syncthreads();
        for (int st = 128; st > 0; st >>= 1) {
            if (tid < st) {
                float od = rD[tid + st]; int oi = rI[tid + st];
                if (od < rD[tid] || (od == rD[tid] && oi < rI[tid])) { rD[tid] = od; rI[tid] = oi; }
            }
            __syncthreads();
        }
        if (tid == 0) ind[p] = rI[0];
        __syncthreads();
    }
}

// -------- final: quantize gather + embed_ind + diff partials --------
__global__ __launch_bounds__(256) void vq_final(
    const float* __restrict__ x, const float* __restrict__ embed,
    const int* __restrict__ ind, float* __restrict__ out,
    float* __restrict__ diff_partial)
{
    __shared__ int bl[64];
    __shared__ float wsum[4];
    const int tid = threadIdx.x;
    const int bid = blockIdx.x;      // (b,h) row: 64 pixels
    const int b = bid >> 6;
    if (tid < 64) {
        int e = ind[bid * 64 + tid];
        bl[tid] = e;
        out[(size_t)QN + 1 + (size_t)bid * 64 + tid] = (float)e;
    }
    __syncthreads();
    const int h = bid & 63;
    float local = 0.f;
    for (int it = 0; it < 64; ++it) {
        int i = it * 256 + tid;
        int c = i >> 6, w = i & 63;
        int e = bl[w];
        float q = embed[c * N_EMB + e];
        size_t o = (((size_t)(b * C_DIM + c)) << 12) + h * 64 + w;
        out[o] = q;
        float dv = q - x[o];
        local = fmaf(dv, dv, local);
    }
    #pragma unroll
    for (int off = 32; off > 0; off >>= 1) local += __shfl_down(local, off);
    if ((tid & 63) == 0) wsum[tid >> 6] = local;
    __syncthreads();
    if (tid == 0) diff_partial[bid] = wsum[0] + wsum[1] + wsum[2] + wsum[3];
}

// -------- finalize diff in f64 --------
__global__ __launch_bounds__(256) void finalize_kernel(const float* __restrict__ part,
                                                       float* __restrict__ out) {
    __shared__ double sd_[256];
    double s = 0.0;
    for (int i = threadIdx.x; i < 1024; i += 256) s += (double)part[i];
    sd_[threadIdx.x] = s;
    __syncthreads();
    for (int st = 128; st > 0; st >>= 1) {
        if (threadIdx.x < st) sd_[threadIdx.x] += sd_[threadIdx.x + st];
        __syncthreads();
    }
    if (threadIdx.x == 0) out[QN] = (float)(sd_[0] / 16777216.0);
}

// ================== round-1 fallback (small ws) ==================
__global__ __launch_bounds__(256) void vq_main_fb(
    const float* __restrict__ x, const float* __restrict__ embed,
    const float* __restrict__ enorm, float* __restrict__ out,
    float* __restrict__ diff_partial)
{
    __shared__ float xs[C_DIM][64];
    __shared__ float es[32 * 128];
    const int tid = threadIdx.x;
    const int bid = blockIdx.x;
    const int b = bid >> 6;
    const int h = bid & 63;
    const float* xb = x + (size_t)(b * C_DIM) * HW + h * 64;
    for (int i = tid; i < C_DIM * 64; i += 256)
        ((float*)xs)[i] = xb[(i >> 6) * HW + (i & 63)];
    __syncthreads();
    const int tp = tid & 15;
    const int te = tid >> 4;
    float xn[4];
    #pragma unroll
    for (int pi = 0; pi < 4; ++pi) {
        int p = tp * 4 + pi;
        float s = 0.f;
        for (int c = 0; c < C_DIM; ++c) s = fmaf(xs[c][p], xs[c][p], s);
        xn[pi] = s;
    }
    float bestd[4]; int besti[4];
    #pragma unroll
    for (int pi = 0; pi < 4; ++pi) { bestd[pi] = 3.0e38f; besti[pi] = 0; }
    for (int ec = 0; ec < 8; ++ec) {
        float acc[4][8];
        #pragma unroll
        for (int pi = 0; pi < 4; ++pi)
            #pragma unroll
            for (int j = 0; j < 8; ++j) acc[pi][j] = 0.f;
        for (int kc = 0; kc < 8; ++kc) {
            __syncthreads();
            for (int i = tid; i < 32 * 128; i += 256) {
                int k = i >> 7, e = i & 127;
                es[i] = embed[(size_t)(kc * 32 + k) * N_EMB + ec * 128 + e];
            }
            __syncthreads();
            #pragma unroll
            for (int k = 0; k < 32; ++k) {
                float4 xv = *(const float4*)&xs[kc * 32 + k][tp * 4];
                float ev[8];
                *(float4*)&ev[0] = *(const float4*)&es[k * 128 + te * 8];
                *(float4*)&ev[4] = *(const float4*)&es[k * 128 + te * 8 + 4];
                #pragma unroll
                for (int pi = 0; pi < 4; ++pi) {
                    float xvv = (&xv.x)[pi];
                    #pragma unroll
                    for (int j = 0; j < 8; ++j)
                        acc[pi][j] = fmaf(xvv, ev[j], acc[pi][j]);
                }
            }
        }
        #pragma unroll
        for (int pi = 0; pi < 4; ++pi)
            #pragma unroll
            for (int j = 0; j < 8; ++j) {
                int e = ec * 128 + te * 8 + j;
                float d = (xn[pi] - 2.0f * acc[pi][j]) + enorm[e];
                if (d < bestd[pi]) { bestd[pi] = d; besti[pi] = e; }
            }
    }
    float* redD = es;
    int*   redI = (int*)(es + 1024);
    int*   best = (int*)(es + 2048);
    float* wsum = es + 3072;
    __syncthreads();
    #pragma unroll
    for (int pi = 0; pi < 4; ++pi) {
        int p = tp * 4 + pi;
        redD[te * 64 + p] = bestd[pi];
        redI[te * 64 + p] = besti[pi];
    }
    __syncthreads();
    if (tid < 64) {
        int p = tid;
        float bd = redD[p]; int bi = redI[p];
        #pragma unroll
        for (int gg = 1; gg < 16; ++gg) {
            float d = redD[gg * 64 + p]; int i2 = redI[gg * 64 + p];
            if (d < bd || (d == bd && i2 < bi)) { bd = d; bi = i2; }
        }
        best[p] = bi;
        out[(size_t)QN + 1 + (size_t)bid * 64 + p] = (float)bi;
    }
    __syncthreads();
    float local = 0.f;
    for (int i = tid; i < C_DIM * 64; i += 256) {
        int c = i >> 6, w = i & 63;
        int e = best[w];
        float q = embed[c * N_EMB + e];
        out[(size_t)(b * C_DIM + c) * HW + h * 64 + w] = q;
        float dv = q - xs[c][w];
        local = fmaf(dv, dv, local);
    }
    #pragma unroll
    for (int off = 32; off > 0; off >>= 1) local += __shfl_down(local, off);
    if ((tid & 63) == 0) wsum[tid >> 6] = local;
    __syncthreads();
    if (tid == 0) diff_partial[bid] = wsum[0] + wsum[1] + wsum[2] + wsum[3];
}

extern "C" void kernel_launch(void* const* d_in, const int* in_sizes, int n_in,
                              void* d_out, int out_size, void* d_ws, size_t ws_size,
                              hipStream_t stream) {
    const float* x     = (const float*)d_in[0];
    const float* embed = (const float*)d_in[1];
    float* out = (float*)d_out;
    char*  ws  = (char*)d_ws;

    if (ws_size >= 82ull * 1048576ull) {
        short* Ap    = (short*)(ws);                     // 64 MB
        short* Bp    = (short*)(ws + (64ull << 20));     // 1 MB
        float* enorm = (float*)(ws + (65ull << 20));     // 4 KB
        float* pB    = (float*)(ws + (66ull << 20));     // 4 MB
        float* pS    = (float*)(ws + (70ull << 20));     // 4 MB
        int*   pI    = (int*)  (ws + (74ull << 20));     // 4 MB
        int*   ind   = (int*)  (ws + (78ull << 20));     // 256 KB
        int*   list  = (int*)  (ws + (79ull << 20));     // 1 MB
        int*   cnt   = (int*)  (ws + (80ull << 20));     // 4 B
        float* part  = (float*)(ws + (80ull << 20) + 4096);

        hipMemsetAsync(cnt, 0, 4, stream);
        enorm_kernel<<<4, 256, 0, stream>>>(embed, enorm);
        prep_a<<<16384, 256, 0, stream>>>(x, Ap);
        prep_b<<<256, 256, 0, stream>>>(embed, Bp);
        vq_gemm<<<4096, 256, 0, stream>>>(Ap, Bp, enorm, pB, pS, pI);
        vq_reduce<<<256, 256, 0, stream>>>(pB, pS, pI, ind, list, cnt);
        vq_fixup<<<1024, 256, 0, stream>>>(x, embed, enorm, list, cnt, ind);
        vq_final<<<1024, 256, 0, stream>>>(x, embed, ind, out, part);
        finalize_kernel<<<1, 256, 0, stream>>>(part, out);
    } else {
        float* enorm = (float*)ws;
        float* part  = enorm + 1024;
        enorm_kernel<<<4, 256, 0, stream>>>(embed, enorm);
        vq_main_fb<<<1024, 256, 0, stream>>>(x, embed, enorm, out, part);
        finalize_kernel<<<1, 256, 0, stream>>>(part, out);
    }
}

// Round 5
// 277.405 us; speedup vs baseline: 3.2690x; 1.2170x over previous
//
#include <hip/hip_runtime.h>
#include <float.h>

#define C_DIM 256
#define N_EMB 1024
#define HW    4096          // 64*64
#define QN    16777216      // quantize element count
#define NPIX  65536
#define TAU   4.0e-3f

typedef __attribute__((ext_vector_type(8))) short short8;
typedef __attribute__((ext_vector_type(4))) float f32x4;
typedef unsigned long long u64;
typedef unsigned int u32;
typedef unsigned short u16;

__device__ __forceinline__ u16 f2bf(float f) {
    u32 u = __float_as_uint(f);
    return (u16)((u + 0x7FFF + ((u >> 16) & 1)) >> 16);   // RN-even, inputs finite
}
__device__ __forceinline__ float bf2f(u16 h) { return __uint_as_float(((u32)h) << 16); }
__device__ __forceinline__ u64 pack4(u16 a, u16 b, u16 c, u16 d) {
    return (u64)a | ((u64)b << 16) | ((u64)c << 32) | ((u64)d << 48);
}

#define GL2LDS(gp, lp) __builtin_amdgcn_global_load_lds(                         \
    (const __attribute__((address_space(1))) u32*)(gp),                          \
    (__attribute__((address_space(3))) u32*)(lp), 16, 0, 0)

// -------- kernel: ||e||^2 per code --------
__global__ __launch_bounds__(256) void enorm_kernel(const float* __restrict__ embed,
                                                    float* __restrict__ enorm) {
    int e = blockIdx.x * 256 + threadIdx.x;
    float s = 0.f;
    #pragma unroll 8
    for (int c = 0; c < C_DIM; ++c) {
        float v = embed[c * N_EMB + e];
        s = fmaf(v, v, s);
    }
    enorm[e] = s;
}

// -------- prep A': x -> packed swizzled bf16 hi|lo tiles --------
// Ap layout: [mb 512][kc 8][m 128][64 shorts: slots swizzled (slot ^ (m&7))]
// split-K fragment: slot g shorts 0..3 = k g*4..+3, shorts 4..7 = 16+g*4..+3
__global__ __launch_bounds__(256) void prep_a(const float* __restrict__ x,
                                              short* __restrict__ Ap) {
    int item = blockIdx.x * 256 + threadIdx.x;   // cg*65536 + pix
    int pix = item & 65535;
    int cg  = item >> 16;                        // 0..63, 4 channels each
    int b = pix >> 12, hw = pix & 4095;
    const float* xp = x + (((size_t)(b * C_DIM + cg * 4)) << 12) + hw;
    float v0 = xp[0], v1 = xp[4096], v2 = xp[8192], v3 = xp[12288];
    u16 h0 = f2bf(v0), h1 = f2bf(v1), h2 = f2bf(v2), h3 = f2bf(v3);
    u16 l0 = f2bf(v0 - bf2f(h0)), l1 = f2bf(v1 - bf2f(h1));
    u16 l2 = f2bf(v2 - bf2f(h2)), l3 = f2bf(v3 - bf2f(h3));
    int m = pix & 127, mb = pix >> 7;
    int kc = cg >> 3, cg3 = cg & 7;
    int s = cg3 & 3;
    int half = (cg3 >> 2) << 2;
    size_t row = (((size_t)(mb * 8 + kc)) * 128 + m) * 64;
    int khi = ((s ^ (m & 7)) << 3) + half;
    int klo = (((s + 4) ^ (m & 7)) << 3) + half;
    *(u64*)(Ap + row + khi) = pack4(h0, h1, h2, h3);
    *(u64*)(Ap + row + klo) = pack4(l0, l1, l2, l3);
}

// -------- prep B': embed -> packed swizzled bf16 hi|lo tiles --------
// Bp layout: [nb 8][kc 8][e 128][64 shorts], same swizzle with (e&7)
__global__ __launch_bounds__(256) void prep_b(const float* __restrict__ embed,
                                              short* __restrict__ Bp) {
    int item = blockIdx.x * 256 + threadIdx.x;   // cg*1024 + e
    int e  = item & 1023;
    int cg = item >> 10;                         // 0..63
    const float* ep = embed + (size_t)(cg * 4) * N_EMB + e;
    float v0 = ep[0], v1 = ep[1024], v2 = ep[2048], v3 = ep[3072];
    u16 h0 = f2bf(v0), h1 = f2bf(v1), h2 = f2bf(v2), h3 = f2bf(v3);
    u16 l0 = f2bf(v0 - bf2f(h0)), l1 = f2bf(v1 - bf2f(h1));
    u16 l2 = f2bf(v2 - bf2f(h2)), l3 = f2bf(v3 - bf2f(h3));
    int eb = e & 127, nb = e >> 7;
    int kc = cg >> 3, cg3 = cg & 7;
    int s = cg3 & 3;
    int half = (cg3 >> 2) << 2;
    size_t row = (((size_t)(nb * 8 + kc)) * 128 + eb) * 64;
    int khi = ((s ^ (eb & 7)) << 3) + half;
    int klo = (((s + 4) ^ (eb & 7)) << 3) + half;
    *(u64*)(Bp + row + khi) = pack4(h0, h1, h2, h3);
    *(u64*)(Bp + row + klo) = pack4(l0, l1, l2, l3);
}

// -------- main MFMA distance GEMM: one block per mb, all 1024 codes --------
// 2-phase double-buffered LDS pipeline; running argmin in registers.
__global__ __launch_bounds__(256, 2) void vq_gemm(
    const short* __restrict__ Ap, const short* __restrict__ Bp,
    const float* __restrict__ enorm,
    int* __restrict__ ind, int* __restrict__ list, int* __restrict__ cnt)
{
    __shared__ __align__(1024) short As[2][8192];   // [buf][m 128][64]
    __shared__ __align__(1024) short Bs[2][8192];   // [buf][e 128][64]
    __shared__ float mD[2][128];
    __shared__ float mS[2][128];
    __shared__ int   mI[2][128];

    const int tid  = threadIdx.x;
    const int mb   = blockIdx.x;      // 0..511
    const int wave = tid >> 6;
    const int lane = tid & 63;
    const int wm   = wave & 1;        // row-group of wave (64 rows)
    const int wn   = wave >> 1;       // col-group of wave (64 cols within 128-chunk)
    const int col  = lane & 15;
    const int g    = lane >> 4;       // 0..3

    const short* Abase = Ap + (size_t)mb * 65536;

    // running per-thread (best, second, idx)
    float bd[4][4], sdv[4][4];
    int   bi[4][4];
    #pragma unroll
    for (int mi = 0; mi < 4; ++mi)
        #pragma unroll
        for (int reg = 0; reg < 4; ++reg) { bd[mi][reg] = FLT_MAX; sdv[mi][reg] = FLT_MAX; bi[mi][reg] = 0x7fffffff; }

    // stage step t into buffer buf
    auto STAGE = [&](int buf, int t) {
        int nb_ = t >> 3, kc_ = t & 7;
        const short* ga = Abase + kc_ * 8192;
        const short* gb = Bp + (size_t)(nb_ * 8 + kc_) * 8192;
        #pragma unroll
        for (int i = 0; i < 4; ++i) {
            int off = (i * 4 + wave) * 512 + lane * 8;   // shorts
            GL2LDS(ga + off, &As[buf][off]);
            GL2LDS(gb + off, &Bs[buf][off]);
        }
    };

    STAGE(0, 0);
    __syncthreads();          // drains vmcnt(0): buf0 ready
    int cur = 0;

    for (int nb = 0; nb < 8; ++nb) {
        float en[4];
        #pragma unroll
        for (int ni = 0; ni < 4; ++ni)
            en[ni] = enorm[nb * 128 + wn * 64 + ni * 16 + col];

        f32x4 acc[4][4];
        #pragma unroll
        for (int mi = 0; mi < 4; ++mi)
            #pragma unroll
            for (int ni = 0; ni < 4; ++ni)
                acc[mi][ni] = (f32x4)0.0f;

        for (int kc = 0; kc < 8; ++kc) {
            int t = nb * 8 + kc;
            if (t < 63) STAGE(cur ^ 1, t + 1);     // prefetch next step (overlaps MFMA)

            short8 ahi[4], alo[4], bhi[4], blo[4];
            #pragma unroll
            for (int mi = 0; mi < 4; ++mi) {
                int r = wm * 64 + mi * 16 + col;
                int base = r * 64;
                ahi[mi] = *(const short8*)&As[cur][base + ((g ^ (r & 7)) << 3)];
                alo[mi] = *(const short8*)&As[cur][base + (((g + 4) ^ (r & 7)) << 3)];
            }
            #pragma unroll
            for (int ni = 0; ni < 4; ++ni) {
                int r = wn * 64 + ni * 16 + col;
                int base = r * 64;
                bhi[ni] = *(const short8*)&Bs[cur][base + ((g ^ (r & 7)) << 3)];
                blo[ni] = *(const short8*)&Bs[cur][base + (((g + 4) ^ (r & 7)) << 3)];
            }
            #pragma unroll
            for (int mi = 0; mi < 4; ++mi)
                #pragma unroll
                for (int ni = 0; ni < 4; ++ni) {
                    acc[mi][ni] = __builtin_amdgcn_mfma_f32_16x16x32_bf16(ahi[mi], bhi[ni], acc[mi][ni], 0, 0, 0);
                    acc[mi][ni] = __builtin_amdgcn_mfma_f32_16x16x32_bf16(ahi[mi], blo[ni], acc[mi][ni], 0, 0, 0);
                    acc[mi][ni] = __builtin_amdgcn_mfma_f32_16x16x32_bf16(alo[mi], bhi[ni], acc[mi][ni], 0, 0, 0);
                }
            __syncthreads();   // drains vmcnt(0)+lgkmcnt: next buf staged, this buf free
            cur ^= 1;
        }

        // fold this nb-chunk into running argmin (code idx ascends over (nb,ni) -> strict <)
        #pragma unroll
        for (int mi = 0; mi < 4; ++mi)
            #pragma unroll
            for (int reg = 0; reg < 4; ++reg)
                #pragma unroll
                for (int ni = 0; ni < 4; ++ni) {
                    float d = en[ni] - 2.0f * acc[mi][ni][reg];
                    if (d < bd[mi][reg]) { sdv[mi][reg] = bd[mi][reg]; bd[mi][reg] = d; bi[mi][reg] = nb * 128 + wn * 64 + ni * 16 + col; }
                    else                 { sdv[mi][reg] = fminf(sdv[mi][reg], d); }
                }
    }

    // cross-col shfl reduce, then cross-wn LDS merge
    #pragma unroll
    for (int mi = 0; mi < 4; ++mi) {
        #pragma unroll
        for (int reg = 0; reg < 4; ++reg) {
            float b = bd[mi][reg], s2 = sdv[mi][reg];
            int   i2 = bi[mi][reg];
            #pragma unroll
            for (int mask = 1; mask < 16; mask <<= 1) {
                float ob = __shfl_xor(b, mask);
                float os = __shfl_xor(s2, mask);
                int   oi = __shfl_xor(i2, mask);
                if (ob < b || (ob == b && oi < i2)) { s2 = fminf(b, os); b = ob; i2 = oi; }
                else                                { s2 = fminf(s2, ob); }
            }
            if (col == 0) {
                int pl = wm * 64 + mi * 16 + g * 4 + reg;   // 0..127
                mD[wn][pl] = b; mS[wn][pl] = s2; mI[wn][pl] = i2;
            }
        }
    }
    __syncthreads();
    if (tid < 128) {
        float b0 = mD[0][tid], s0 = mS[0][tid];
        int   i0 = mI[0][tid];
        float b1 = mD[1][tid], s1 = mS[1][tid];
        int   i1 = mI[1][tid];
        float b, s; int i;
        if (b1 < b0 || (b1 == b0 && i1 < i0)) { b = b1; i = i1; s = fminf(b0, s1); }
        else                                  { b = b0; i = i0; s = fminf(s0, b1); }
        int p = mb * 128 + tid;
        ind[p] = i;
        if (s - b < TAU) {
            int pos = atomicAdd(cnt, 1);
            list[pos] = p;
        }
    }
}

// -------- exact f32 re-check for ambiguous pixels (round-1 numerics) --------
__global__ __launch_bounds__(256) void vq_fixup(
    const float* __restrict__ x, const float* __restrict__ embed,
    const float* __restrict__ enorm, const int* __restrict__ list,
    const int* __restrict__ cnt, int* __restrict__ ind)
{
    __shared__ float xr[256];
    __shared__ float xnsh;
    __shared__ float rD[256];
    __shared__ int   rI[256];
    const int tid = threadIdx.x;
    const int nfix = cnt[0];

    for (int j = blockIdx.x; j < nfix; j += gridDim.x) {
        int p = list[j];
        int b = p >> 12, hw = p & 4095;
        xr[tid] = x[(((size_t)(b * C_DIM + tid)) << 12) + hw];
        __syncthreads();
        if (tid == 0) {
            float s = 0.f;
            for (int c = 0; c < C_DIM; ++c) s = fmaf(xr[c], xr[c], s);
            xnsh = s;
        }
        __syncthreads();
        float xn = xnsh;
        float best = FLT_MAX; int bidx = 0;
        #pragma unroll
        for (int j4 = 0; j4 < 4; ++j4) {
            int e = j4 * 256 + tid;
            float acc = 0.f;
            for (int c = 0; c < C_DIM; ++c) acc = fmaf(xr[c], embed[c * N_EMB + e], acc);
            float d = (xn - 2.0f * acc) + enorm[e];
            if (d < best) { best = d; bidx = e; }
        }
        rD[tid] = best; rI[tid] = bidx;
        __syncthreads();
        for (int st = 128; st > 0; st >>= 1) {
            if (tid < st) {
                float od = rD[tid + st]; int oi = rI[tid + st];
                if (od < rD[tid] || (od == rD[tid] && oi < rI[tid])) { rD[tid] = od; rI[tid] = oi; }
            }
            __syncthreads();
        }
        if (tid == 0) ind[p] = rI[0];
        __syncthreads();
    }
}

// -------- final: quantize gather + embed_ind + diff partials --------
__global__ __launch_bounds__(256) void vq_final(
    const float* __restrict__ x, const float* __restrict__ embed,
    const int* __restrict__ ind, float* __restrict__ out,
    float* __restrict__ diff_partial)
{
    __shared__ int bl[64];
    __shared__ float wsum[4];
    const int tid = threadIdx.x;
    const int bid = blockIdx.x;      // (b,h) row: 64 pixels
    const int b = bid >> 6;
    if (tid < 64) {
        int e = ind[bid * 64 + tid];
        bl[tid] = e;
        out[(size_t)QN + 1 + (size_t)bid * 64 + tid] = (float)e;
    }
    __syncthreads();
    const int h = bid & 63;
    float local = 0.f;
    for (int it = 0; it < 64; ++it) {
        int i = it * 256 + tid;
        int c = i >> 6, w = i & 63;
        int e = bl[w];
        float q = embed[c * N_EMB + e];
        size_t o = (((size_t)(b * C_DIM + c)) << 12) + h * 64 + w;
        out[o] = q;
        float dv = q - x[o];
        local = fmaf(dv, dv, local);
    }
    #pragma unroll
    for (int off = 32; off > 0; off >>= 1) local += __shfl_down(local, off);
    if ((tid & 63) == 0) wsum[tid >> 6] = local;
    __syncthreads();
    if (tid == 0) diff_partial[bid] = wsum[0] + wsum[1] + wsum[2] + wsum[3];
}

// -------- finalize diff in f64 --------
__global__ __launch_bounds__(256) void finalize_kernel(const float* __restrict__ part,
                                                       float* __restrict__ out) {
    __shared__ double sd_[256];
    double s = 0.0;
    for (int i = threadIdx.x; i < 1024; i += 256) s += (double)part[i];
    sd_[threadIdx.x] = s;
    __syncthreads();
    for (int st = 128; st > 0; st >>= 1) {
        if (threadIdx.x < st) sd_[threadIdx.x] += sd_[threadIdx.x + st];
        __syncthreads();
    }
    if (threadIdx.x == 0) out[QN] = (float)(sd_[0] / 16777216.0);
}

// ================== round-1 fallback (small ws) ==================
__global__ __launch_bounds__(256) void vq_main_fb(
    const float* __restrict__ x, const float* __restrict__ embed,
    const float* __restrict__ enorm, float* __restrict__ out,
    float* __restrict__ diff_partial)
{
    __shared__ float xs[C_DIM][64];
    __shared__ float es[32 * 128];
    const int tid = threadIdx.x;
    const int bid = blockIdx.x;
    const int b = bid >> 6;
    const int h = bid & 63;
    const float* xb = x + (size_t)(b * C_DIM) * HW + h * 64;
    for (int i = tid; i < C_DIM * 64; i += 256)
        ((float*)xs)[i] = xb[(i >> 6) * HW + (i & 63)];
    __syncthreads();
    const int tp = tid & 15;
    const int te = tid >> 4;
    float xn[4];
    #pragma unroll
    for (int pi = 0; pi < 4; ++pi) {
        int p = tp * 4 + pi;
        float s = 0.f;
        for (int c = 0; c < C_DIM; ++c) s = fmaf(xs[c][p], xs[c][p], s);
        xn[pi] = s;
    }
    float bestd[4]; int besti[4];
    #pragma unroll
    for (int pi = 0; pi < 4; ++pi) { bestd[pi] = 3.0e38f; besti[pi] = 0; }
    for (int ec = 0; ec < 8; ++ec) {
        float acc[4][8];
        #pragma unroll
        for (int pi = 0; pi < 4; ++pi)
            #pragma unroll
            for (int j = 0; j < 8; ++j) acc[pi][j] = 0.f;
        for (int kc = 0; kc < 8; ++kc) {
            __syncthreads();
            for (int i = tid; i < 32 * 128; i += 256) {
                int k = i >> 7, e = i & 127;
                es[i] = embed[(size_t)(kc * 32 + k) * N_EMB + ec * 128 + e];
            }
            __syncthreads();
            #pragma unroll
            for (int k = 0; k < 32; ++k) {
                float4 xv = *(const float4*)&xs[kc * 32 + k][tp * 4];
                float ev[8];
                *(float4*)&ev[0] = *(const float4*)&es[k * 128 + te * 8];
                *(float4*)&ev[4] = *(const float4*)&es[k * 128 + te * 8 + 4];
                #pragma unroll
                for (int pi = 0; pi < 4; ++pi) {
                    float xvv = (&xv.x)[pi];
                    #pragma unroll
                    for (int j = 0; j < 8; ++j)
                        acc[pi][j] = fmaf(xvv, ev[j], acc[pi][j]);
                }
            }
        }
        #pragma unroll
        for (int pi = 0; pi < 4; ++pi)
            #pragma unroll
            for (int j = 0; j < 8; ++j) {
                int e = ec * 128 + te * 8 + j;
                float d = (xn[pi] - 2.0f * acc[pi][j]) + enorm[e];
                if (d < bestd[pi]) { bestd[pi] = d; besti[pi] = e; }
            }
    }
    float* redD = es;
    int*   redI = (int*)(es + 1024);
    int*   best = (int*)(es + 2048);
    float* wsum = es + 3072;
    __syncthreads();
    #pragma unroll
    for (int pi = 0; pi < 4; ++pi) {
        int p = tp * 4 + pi;
        redD[te * 64 + p] = bestd[pi];
        redI[te * 64 + p] = besti[pi];
    }
    __syncthreads();
    if (tid < 64) {
        int p = tid;
        float bdv = redD[p]; int biv = redI[p];
        #pragma unroll
        for (int gg = 1; gg < 16; ++gg) {
            float d = redD[gg * 64 + p]; int i2 = redI[gg * 64 + p];
            if (d < bdv || (d == bdv && i2 < biv)) { bdv = d; biv = i2; }
        }
        best[p] = biv;
        out[(size_t)QN + 1 + (size_t)bid * 64 + p] = (float)biv;
    }
    __syncthreads();
    float local = 0.f;
    for (int i = tid; i < C_DIM * 64; i += 256) {
        int c = i >> 6, w = i & 63;
        int e = best[w];
        float q = embed[c * N_EMB + e];
        out[(size_t)(b * C_DIM + c) * HW + h * 64 + w] = q;
        float dv = q - xs[c][w];
        local = fmaf(dv, dv, local);
    }
    #pragma unroll
    for (int off = 32; off > 0; off >>= 1) local += __shfl_down(local, off);
    if ((tid & 63) == 0) wsum[tid >> 6] = local;
    __syncthreads();
    if (tid == 0) diff_partial[bid] = wsum[0] + wsum[1] + wsum[2] + wsum[3];
}

extern "C" void kernel_launch(void* const* d_in, const int* in_sizes, int n_in,
                              void* d_out, int out_size, void* d_ws, size_t ws_size,
                              hipStream_t stream) {
    const float* x     = (const float*)d_in[0];
    const float* embed = (const float*)d_in[1];
    float* out = (float*)d_out;
    char*  ws  = (char*)d_ws;

    if (ws_size >= 70ull * 1048576ull) {
        short* Ap    = (short*)(ws);                     // 64 MB
        short* Bp    = (short*)(ws + (64ull << 20));     // 1 MB
        float* enorm = (float*)(ws + (65ull << 20));     // 4 KB
        int*   ind   = (int*)  (ws + (66ull << 20));     // 256 KB
        int*   list  = (int*)  (ws + (67ull << 20));     // 256 KB
        int*   cnt   = (int*)  (ws + (68ull << 20));     // 4 B
        float* part  = (float*)(ws + (68ull << 20) + 4096);

        hipMemsetAsync(cnt, 0, 4, stream);
        enorm_kernel<<<4, 256, 0, stream>>>(embed, enorm);
        prep_a<<<16384, 256, 0, stream>>>(x, Ap);
        prep_b<<<256, 256, 0, stream>>>(embed, Bp);
        vq_gemm<<<512, 256, 0, stream>>>(Ap, Bp, enorm, ind, list, cnt);
        vq_fixup<<<1024, 256, 0, stream>>>(x, embed, enorm, list, cnt, ind);
        vq_final<<<1024, 256, 0, stream>>>(x, embed, ind, out, part);
        finalize_kernel<<<1, 256, 0, stream>>>(part, out);
    } else {
        float* enorm = (float*)ws;
        float* part  = enorm + 1024;
        enorm_kernel<<<4, 256, 0, stream>>>(embed, enorm);
        vq_main_fb<<<1024, 256, 0, stream>>>(x, embed, enorm, out, part);
        finalize_kernel<<<1, 256, 0, stream>>>(part, out);
    }
}

// Round 6
// 261.932 us; speedup vs baseline: 3.4621x; 1.0591x over previous
//
#include <hip/hip_runtime.h>
#include <float.h>

#define C_DIM 256
#define N_EMB 1024
#define HW    4096          // 64*64
#define QN    16777216      // quantize element count
#define NPIX  65536
#define TAU   4.0e-3f

typedef __attribute__((ext_vector_type(8))) short short8;
typedef __attribute__((ext_vector_type(4))) float f32x4;
typedef unsigned long long u64;
typedef unsigned int u32;
typedef unsigned short u16;

__device__ __forceinline__ u16 f2bf(float f) {
    u32 u = __float_as_uint(f);
    return (u16)((u + 0x7FFF + ((u >> 16) & 1)) >> 16);   // RN-even, inputs finite
}
__device__ __forceinline__ float bf2f(u16 h) { return __uint_as_float(((u32)h) << 16); }
__device__ __forceinline__ u64 pack4(u16 a, u16 b, u16 c, u16 d) {
    return (u64)a | ((u64)b << 16) | ((u64)c << 32) | ((u64)d << 48);
}

#define GL2LDS(gp, lp) __builtin_amdgcn_global_load_lds(                         \
    (const __attribute__((address_space(1))) u32*)(gp),                          \
    (__attribute__((address_space(3))) u32*)(lp), 16, 0, 0)

// -------- kernel: ||e||^2 per code --------
__global__ __launch_bounds__(256) void enorm_kernel(const float* __restrict__ embed,
                                                    float* __restrict__ enorm) {
    int e = blockIdx.x * 256 + threadIdx.x;
    float s = 0.f;
    #pragma unroll 8
    for (int c = 0; c < C_DIM; ++c) {
        float v = embed[c * N_EMB + e];
        s = fmaf(v, v, s);
    }
    enorm[e] = s;
}

// -------- prep A': x -> packed swizzled bf16 hi|lo tiles --------
// Ap layout: [mb 512][kc 8][m 128][64 shorts: slots swizzled (slot ^ (m&7))]
// split-K fragment: slot g shorts 0..3 = k g*4..+3, shorts 4..7 = 16+g*4..+3
__global__ __launch_bounds__(256) void prep_a(const float* __restrict__ x,
                                              short* __restrict__ Ap) {
    int item = blockIdx.x * 256 + threadIdx.x;   // cg*65536 + pix
    int pix = item & 65535;
    int cg  = item >> 16;                        // 0..63, 4 channels each
    int b = pix >> 12, hw = pix & 4095;
    const float* xp = x + (((size_t)(b * C_DIM + cg * 4)) << 12) + hw;
    float v0 = xp[0], v1 = xp[4096], v2 = xp[8192], v3 = xp[12288];
    u16 h0 = f2bf(v0), h1 = f2bf(v1), h2 = f2bf(v2), h3 = f2bf(v3);
    u16 l0 = f2bf(v0 - bf2f(h0)), l1 = f2bf(v1 - bf2f(h1));
    u16 l2 = f2bf(v2 - bf2f(h2)), l3 = f2bf(v3 - bf2f(h3));
    int m = pix & 127, mb = pix >> 7;
    int kc = cg >> 3, cg3 = cg & 7;
    int s = cg3 & 3;
    int half = (cg3 >> 2) << 2;
    size_t row = (((size_t)(mb * 8 + kc)) * 128 + m) * 64;
    int khi = ((s ^ (m & 7)) << 3) + half;
    int klo = (((s + 4) ^ (m & 7)) << 3) + half;
    *(u64*)(Ap + row + khi) = pack4(h0, h1, h2, h3);
    *(u64*)(Ap + row + klo) = pack4(l0, l1, l2, l3);
}

// -------- prep B': embed -> packed swizzled bf16 hi|lo tiles --------
// Bp layout: [nb 8][kc 8][e 128][64 shorts], same swizzle with (e&7)
__global__ __launch_bounds__(256) void prep_b(const float* __restrict__ embed,
                                              short* __restrict__ Bp) {
    int item = blockIdx.x * 256 + threadIdx.x;   // cg*1024 + e
    int e  = item & 1023;
    int cg = item >> 10;                         // 0..63
    const float* ep = embed + (size_t)(cg * 4) * N_EMB + e;
    float v0 = ep[0], v1 = ep[1024], v2 = ep[2048], v3 = ep[3072];
    u16 h0 = f2bf(v0), h1 = f2bf(v1), h2 = f2bf(v2), h3 = f2bf(v3);
    u16 l0 = f2bf(v0 - bf2f(h0)), l1 = f2bf(v1 - bf2f(h1));
    u16 l2 = f2bf(v2 - bf2f(h2)), l3 = f2bf(v3 - bf2f(h3));
    int eb = e & 127, nb = e >> 7;
    int kc = cg >> 3, cg3 = cg & 7;
    int s = cg3 & 3;
    int half = (cg3 >> 2) << 2;
    size_t row = (((size_t)(nb * 8 + kc)) * 128 + eb) * 64;
    int khi = ((s ^ (eb & 7)) << 3) + half;
    int klo = (((s + 4) ^ (eb & 7)) << 3) + half;
    *(u64*)(Bp + row + khi) = pack4(h0, h1, h2, h3);
    *(u64*)(Bp + row + klo) = pack4(l0, l1, l2, l3);
}

// -------- main MFMA distance GEMM: one block per mb, all 1024 codes --------
// Counted-vmcnt deep pipeline (T4): prefetch stays in flight across barriers;
// barrier1 = buf ready (after per-wave vmcnt(8)), barrier2 = reads done.
__global__ __launch_bounds__(256, 2) void vq_gemm(
    const short* __restrict__ Ap, const short* __restrict__ Bp,
    const float* __restrict__ enorm,
    int* __restrict__ ind, int* __restrict__ list, int* __restrict__ cnt)
{
    __shared__ __align__(1024) short As[2][8192];   // [buf][m 128][64]
    __shared__ __align__(1024) short Bs[2][8192];   // [buf][e 128][64]
    __shared__ float eLDS[1024];                    // ||e||^2 (keeps vmem domain clean)
    __shared__ float mD[2][128];
    __shared__ float mS[2][128];
    __shared__ int   mI[2][128];

    const int tid  = threadIdx.x;
    const int mb   = blockIdx.x;      // 0..511
    const int wave = tid >> 6;
    const int lane = tid & 63;
    const int wm   = wave & 1;        // row-group of wave (64 rows)
    const int wn   = wave >> 1;       // col-group of wave (64 cols within 128-chunk)
    const int col  = lane & 15;
    const int g    = lane >> 4;       // 0..3

    const short* Abase = Ap + (size_t)mb * 65536;

    // running per-thread (best, second, idx)
    float bd[4][4], sdv[4][4];
    int   bi[4][4];
    #pragma unroll
    for (int mi = 0; mi < 4; ++mi)
        #pragma unroll
        for (int reg = 0; reg < 4; ++reg) { bd[mi][reg] = FLT_MAX; sdv[mi][reg] = FLT_MAX; bi[mi][reg] = 0x7fffffff; }

    // stage step t into buffer buf (8 GL2LDS per wave — vmcnt accounting relies on this)
    auto STAGE = [&](int buf, int t) {
        int nb_ = t >> 3, kc_ = t & 7;
        const short* ga = Abase + kc_ * 8192;
        const short* gb = Bp + (size_t)(nb_ * 8 + kc_) * 8192;
        #pragma unroll
        for (int i = 0; i < 4; ++i) {
            int off = (i * 4 + wave) * 512 + lane * 8;   // shorts
            GL2LDS(ga + off, &As[buf][off]);
            GL2LDS(gb + off, &Bs[buf][off]);
        }
    };

    // prologue: enorm -> LDS, stage step 0, full drain once
    for (int i = tid; i < 1024; i += 256) eLDS[i] = enorm[i];
    STAGE(0, 0);
    __syncthreads();
    int cur = 0;

    f32x4 acc[4][4];
    for (int t = 0; t < 64; ++t) {
        const int kc7 = (t & 7) == 7;
        if ((t & 7) == 0) {
            #pragma unroll
            for (int mi = 0; mi < 4; ++mi)
                #pragma unroll
                for (int ni = 0; ni < 4; ++ni)
                    acc[mi][ni] = (f32x4)0.0f;
        }

        if (t < 63) {
            STAGE(cur ^ 1, t + 1);
            asm volatile("s_waitcnt vmcnt(8)" ::: "memory");   // STAGE(t) landed; STAGE(t+1) in flight
        } else {
            asm volatile("s_waitcnt vmcnt(0)" ::: "memory");
        }
        __builtin_amdgcn_sched_barrier(0);
        __builtin_amdgcn_s_barrier();        // barrier1: everyone's buf[cur] ready
        __builtin_amdgcn_sched_barrier(0);

        short8 ahi[4], alo[4], bhi[4], blo[4];
        #pragma unroll
        for (int mi = 0; mi < 4; ++mi) {
            int r = wm * 64 + mi * 16 + col;
            int base = r * 64;
            ahi[mi] = *(const short8*)&As[cur][base + ((g ^ (r & 7)) << 3)];
            alo[mi] = *(const short8*)&As[cur][base + (((g + 4) ^ (r & 7)) << 3)];
        }
        #pragma unroll
        for (int ni = 0; ni < 4; ++ni) {
            int r = wn * 64 + ni * 16 + col;
            int base = r * 64;
            bhi[ni] = *(const short8*)&Bs[cur][base + ((g ^ (r & 7)) << 3)];
            blo[ni] = *(const short8*)&Bs[cur][base + (((g + 4) ^ (r & 7)) << 3)];
        }
        #pragma unroll
        for (int mi = 0; mi < 4; ++mi)
            #pragma unroll
            for (int ni = 0; ni < 4; ++ni) {
                acc[mi][ni] = __builtin_amdgcn_mfma_f32_16x16x32_bf16(ahi[mi], bhi[ni], acc[mi][ni], 0, 0, 0);
                acc[mi][ni] = __builtin_amdgcn_mfma_f32_16x16x32_bf16(ahi[mi], blo[ni], acc[mi][ni], 0, 0, 0);
                acc[mi][ni] = __builtin_amdgcn_mfma_f32_16x16x32_bf16(alo[mi], bhi[ni], acc[mi][ni], 0, 0, 0);
            }

        if (kc7) {
            int nb = t >> 3;
            float en[4];
            #pragma unroll
            for (int ni = 0; ni < 4; ++ni)
                en[ni] = eLDS[nb * 128 + wn * 64 + ni * 16 + col];
            // fold (code idx ascends over (nb,ni) -> strict <)
            #pragma unroll
            for (int mi = 0; mi < 4; ++mi)
                #pragma unroll
                for (int reg = 0; reg < 4; ++reg)
                    #pragma unroll
                    for (int ni = 0; ni < 4; ++ni) {
                        float d = en[ni] - 2.0f * acc[mi][ni][reg];
                        if (d < bd[mi][reg]) { sdv[mi][reg] = bd[mi][reg]; bd[mi][reg] = d; bi[mi][reg] = nb * 128 + wn * 64 + ni * 16 + col; }
                        else                 { sdv[mi][reg] = fminf(sdv[mi][reg], d); }
                    }
        }

        __builtin_amdgcn_sched_barrier(0);
        __builtin_amdgcn_s_barrier();        // barrier2: all reads of buf[cur] retired
        cur ^= 1;
    }

    // cross-col shfl reduce, then cross-wn LDS merge
    #pragma unroll
    for (int mi = 0; mi < 4; ++mi) {
        #pragma unroll
        for (int reg = 0; reg < 4; ++reg) {
            float b = bd[mi][reg], s2 = sdv[mi][reg];
            int   i2 = bi[mi][reg];
            #pragma unroll
            for (int mask = 1; mask < 16; mask <<= 1) {
                float ob = __shfl_xor(b, mask);
                float os = __shfl_xor(s2, mask);
                int   oi = __shfl_xor(i2, mask);
                if (ob < b || (ob == b && oi < i2)) { s2 = fminf(b, os); b = ob; i2 = oi; }
                else                                { s2 = fminf(s2, ob); }
            }
            if (col == 0) {
                int pl = wm * 64 + mi * 16 + g * 4 + reg;   // 0..127
                mD[wn][pl] = b; mS[wn][pl] = s2; mI[wn][pl] = i2;
            }
        }
    }
    __syncthreads();
    if (tid < 128) {
        float b0 = mD[0][tid], s0 = mS[0][tid];
        int   i0 = mI[0][tid];
        float b1 = mD[1][tid], s1 = mS[1][tid];
        int   i1 = mI[1][tid];
        float b, s; int i;
        if (b1 < b0 || (b1 == b0 && i1 < i0)) { b = b1; i = i1; s = fminf(b0, s1); }
        else                                  { b = b0; i = i0; s = fminf(s0, b1); }
        int p = mb * 128 + tid;
        ind[p] = i;
        if (s - b < TAU) {
            int pos = atomicAdd(cnt, 1);
            list[pos] = p;
        }
    }
}

// -------- exact f32 re-check for ambiguous pixels (round-1 numerics) --------
__global__ __launch_bounds__(256) void vq_fixup(
    const float* __restrict__ x, const float* __restrict__ embed,
    const float* __restrict__ enorm, const int* __restrict__ list,
    const int* __restrict__ cnt, int* __restrict__ ind)
{
    __shared__ float xr[256];
    __shared__ float xnsh;
    __shared__ float rD[256];
    __shared__ int   rI[256];
    const int tid = threadIdx.x;
    const int nfix = cnt[0];

    for (int j = blockIdx.x; j < nfix; j += gridDim.x) {
        int p = list[j];
        int b = p >> 12, hw = p & 4095;
        xr[tid] = x[(((size_t)(b * C_DIM + tid)) << 12) + hw];
        __syncthreads();
        if (tid == 0) {
            float s = 0.f;
            for (int c = 0; c < C_DIM; ++c) s = fmaf(xr[c], xr[c], s);
            xnsh = s;
        }
        __syncthreads();
        float xn = xnsh;
        float best = FLT_MAX; int bidx = 0;
        #pragma unroll
        for (int j4 = 0; j4 < 4; ++j4) {
            int e = j4 * 256 + tid;
            float acc = 0.f;
            for (int c = 0; c < C_DIM; ++c) acc = fmaf(xr[c], embed[c * N_EMB + e], acc);
            float d = (xn - 2.0f * acc) + enorm[e];
            if (d < best) { best = d; bidx = e; }
        }
        rD[tid] = best; rI[tid] = bidx;
        __syncthreads();
        for (int st = 128; st > 0; st >>= 1) {
            if (tid < st) {
                float od = rD[tid + st]; int oi = rI[tid + st];
                if (od < rD[tid] || (od == rD[tid] && oi < rI[tid])) { rD[tid] = od; rI[tid] = oi; }
            }
            __syncthreads();
        }
        if (tid == 0) ind[p] = rI[0];
        __syncthreads();
    }
}

// -------- final: quantize gather + embed_ind + diff partials --------
__global__ __launch_bounds__(256) void vq_final(
    const float* __restrict__ x, const float* __restrict__ embed,
    const int* __restrict__ ind, float* __restrict__ out,
    float* __restrict__ diff_partial)
{
    __shared__ int bl[64];
    __shared__ float wsum[4];
    const int tid = threadIdx.x;
    const int bid = blockIdx.x;      // (b,h) row: 64 pixels
    const int b = bid >> 6;
    if (tid < 64) {
        int e = ind[bid * 64 + tid];
        bl[tid] = e;
        out[(size_t)QN + 1 + (size_t)bid * 64 + tid] = (float)e;
    }
    __syncthreads();
    const int h = bid & 63;
    float local = 0.f;
    for (int it = 0; it < 64; ++it) {
        int i = it * 256 + tid;
        int c = i >> 6, w = i & 63;
        int e = bl[w];
        float q = embed[c * N_EMB + e];
        size_t o = (((size_t)(b * C_DIM + c)) << 12) + h * 64 + w;
        out[o] = q;
        float dv = q - x[o];
        local = fmaf(dv, dv, local);
    }
    #pragma unroll
    for (int off = 32; off > 0; off >>= 1) local += __shfl_down(local, off);
    if ((tid & 63) == 0) wsum[tid >> 6] = local;
    __syncthreads();
    if (tid == 0) diff_partial[bid] = wsum[0] + wsum[1] + wsum[2] + wsum[3];
}

// -------- finalize diff in f64 --------
__global__ __launch_bounds__(256) void finalize_kernel(const float* __restrict__ part,
                                                       float* __restrict__ out) {
    __shared__ double sd_[256];
    double s = 0.0;
    for (int i = threadIdx.x; i < 1024; i += 256) s += (double)part[i];
    sd_[threadIdx.x] = s;
    __syncthreads();
    for (int st = 128; st > 0; st >>= 1) {
        if (threadIdx.x < st) sd_[threadIdx.x] += sd_[threadIdx.x + st];
        __syncthreads();
    }
    if (threadIdx.x == 0) out[QN] = (float)(sd_[0] / 16777216.0);
}

// ================== round-1 fallback (small ws) ==================
__global__ __launch_bounds__(256) void vq_main_fb(
    const float* __restrict__ x, const float* __restrict__ embed,
    const float* __restrict__ enorm, float* __restrict__ out,
    float* __restrict__ diff_partial)
{
    __shared__ float xs[C_DIM][64];
    __shared__ float es[32 * 128];
    const int tid = threadIdx.x;
    const int bid = blockIdx.x;
    const int b = bid >> 6;
    const int h = bid & 63;
    const float* xb = x + (size_t)(b * C_DIM) * HW + h * 64;
    for (int i = tid; i < C_DIM * 64; i += 256)
        ((float*)xs)[i] = xb[(i >> 6) * HW + (i & 63)];
    __syncthreads();
    const int tp = tid & 15;
    const int te = tid >> 4;
    float xn[4];
    #pragma unroll
    for (int pi = 0; pi < 4; ++pi) {
        int p = tp * 4 + pi;
        float s = 0.f;
        for (int c = 0; c < C_DIM; ++c) s = fmaf(xs[c][p], xs[c][p], s);
        xn[pi] = s;
    }
    float bestd[4]; int besti[4];
    #pragma unroll
    for (int pi = 0; pi < 4; ++pi) { bestd[pi] = 3.0e38f; besti[pi] = 0; }
    for (int ec = 0; ec < 8; ++ec) {
        float acc[4][8];
        #pragma unroll
        for (int pi = 0; pi < 4; ++pi)
            #pragma unroll
            for (int j = 0; j < 8; ++j) acc[pi][j] = 0.f;
        for (int kc = 0; kc < 8; ++kc) {
            __syncthreads();
            for (int i = tid; i < 32 * 128; i += 256) {
                int k = i >> 7, e = i & 127;
                es[i] = embed[(size_t)(kc * 32 + k) * N_EMB + ec * 128 + e];
            }
            __syncthreads();
            #pragma unroll
            for (int k = 0; k < 32; ++k) {
                float4 xv = *(const float4*)&xs[kc * 32 + k][tp * 4];
                float ev[8];
                *(float4*)&ev[0] = *(const float4*)&es[k * 128 + te * 8];
                *(float4*)&ev[4] = *(const float4*)&es[k * 128 + te * 8 + 4];
                #pragma unroll
                for (int pi = 0; pi < 4; ++pi) {
                    float xvv = (&xv.x)[pi];
                    #pragma unroll
                    for (int j = 0; j < 8; ++j)
                        acc[pi][j] = fmaf(xvv, ev[j], acc[pi][j]);
                }
            }
        }
        #pragma unroll
        for (int pi = 0; pi < 4; ++pi)
            #pragma unroll
            for (int j = 0; j < 8; ++j) {
                int e = ec * 128 + te * 8 + j;
                float d = (xn[pi] - 2.0f * acc[pi][j]) + enorm[e];
                if (d < bestd[pi]) { bestd[pi] = d; besti[pi] = e; }
            }
    }
    float* redD = es;
    int*   redI = (int*)(es + 1024);
    int*   best = (int*)(es + 2048);
    float* wsum = es + 3072;
    __syncthreads();
    #pragma unroll
    for (int pi = 0; pi < 4; ++pi) {
        int p = tp * 4 + pi;
        redD[te * 64 + p] = bestd[pi];
        redI[te * 64 + p] = besti[pi];
    }
    __syncthreads();
    if (tid < 64) {
        int p = tid;
        float bdv = redD[p]; int biv = redI[p];
        #pragma unroll
        for (int gg = 1; gg < 16; ++gg) {
            float d = redD[gg * 64 + p]; int i2 = redI[gg * 64 + p];
            if (d < bdv || (d == bdv && i2 < biv)) { bdv = d; biv = i2; }
        }
        best[p] = biv;
        out[(size_t)QN + 1 + (size_t)bid * 64 + p] = (float)biv;
    }
    __syncthreads();
    float local = 0.f;
    for (int i = tid; i < C_DIM * 64; i += 256) {
        int c = i >> 6, w = i & 63;
        int e = best[w];
        float q = embed[c * N_EMB + e];
        out[(size_t)(b * C_DIM + c) * HW + h * 64 + w] = q;
        float dv = q - xs[c][w];
        local = fmaf(dv, dv, local);
    }
    #pragma unroll
    for (int off = 32; off > 0; off >>= 1) local += __shfl_down(local, off);
    if ((tid & 63) == 0) wsum[tid >> 6] = local;
    __syncthreads();
    if (tid == 0) diff_partial[bid] = wsum[0] + wsum[1] + wsum[2] + wsum[3];
}

extern "C" void kernel_launch(void* const* d_in, const int* in_sizes, int n_in,
                              void* d_out, int out_size, void* d_ws, size_t ws_size,
                              hipStream_t stream) {
    const float* x     = (const float*)d_in[0];
    const float* embed = (const float*)d_in[1];
    float* out = (float*)d_out;
    char*  ws  = (char*)d_ws;

    if (ws_size >= 70ull * 1048576ull) {
        short* Ap    = (short*)(ws);                     // 64 MB
        short* Bp    = (short*)(ws + (64ull << 20));     // 1 MB
        float* enorm = (float*)(ws + (65ull << 20));     // 4 KB
        int*   ind   = (int*)  (ws + (66ull << 20));     // 256 KB
        int*   list  = (int*)  (ws + (67ull << 20));     // 256 KB
        int*   cnt   = (int*)  (ws + (68ull << 20));     // 4 B
        float* part  = (float*)(ws + (68ull << 20) + 4096);

        hipMemsetAsync(cnt, 0, 4, stream);
        enorm_kernel<<<4, 256, 0, stream>>>(embed, enorm);
        prep_a<<<16384, 256, 0, stream>>>(x, Ap);
        prep_b<<<256, 256, 0, stream>>>(embed, Bp);
        vq_gemm<<<512, 256, 0, stream>>>(Ap, Bp, enorm, ind, list, cnt);
        vq_fixup<<<1024, 256, 0, stream>>>(x, embed, enorm, list, cnt, ind);
        vq_final<<<1024, 256, 0, stream>>>(x, embed, ind, out, part);
        finalize_kernel<<<1, 256, 0, stream>>>(part, out);
    } else {
        float* enorm = (float*)ws;
        float* part  = enorm + 1024;
        enorm_kernel<<<4, 256, 0, stream>>>(embed, enorm);
        vq_main_fb<<<1024, 256, 0, stream>>>(x, embed, enorm, out, part);
        finalize_kernel<<<1, 256, 0, stream>>>(part, out);
    }
}

// Round 7
// 240.523 us; speedup vs baseline: 3.7703x; 1.0890x over previous
//
#include <hip/hip_runtime.h>
#include <float.h>

#define C_DIM 256
#define N_EMB 1024
#define HW    4096          // 64*64
#define QN    16777216      // quantize element count
#define NPIX  65536
#define TAU   4.0e-3f

typedef __attribute__((ext_vector_type(8))) short short8;
typedef __attribute__((ext_vector_type(4))) float f32x4;
typedef unsigned long long u64;
typedef unsigned int u32;
typedef unsigned short u16;

__device__ __forceinline__ u16 f2bf(float f) {
    u32 u = __float_as_uint(f);
    return (u16)((u + 0x7FFF + ((u >> 16) & 1)) >> 16);   // RN-even, inputs finite
}
__device__ __forceinline__ float bf2f(u16 h) { return __uint_as_float(((u32)h) << 16); }
__device__ __forceinline__ u64 pack4(u16 a, u16 b, u16 c, u16 d) {
    return (u64)a | ((u64)b << 16) | ((u64)c << 32) | ((u64)d << 48);
}

#define GL2LDS(gp, lp) __builtin_amdgcn_global_load_lds(                         \
    (const __attribute__((address_space(1))) u32*)(gp),                          \
    (__attribute__((address_space(3))) u32*)(lp), 16, 0, 0)

// -------- kernel: ||e||^2 per code (+ zero the fixup counter) --------
__global__ __launch_bounds__(256) void enorm_kernel(const float* __restrict__ embed,
                                                    float* __restrict__ enorm,
                                                    int* __restrict__ cnt) {
    if (blockIdx.x == 0 && threadIdx.x == 0) cnt[0] = 0;
    int e = blockIdx.x * 256 + threadIdx.x;
    float s = 0.f;
    #pragma unroll 8
    for (int c = 0; c < C_DIM; ++c) {
        float v = embed[c * N_EMB + e];
        s = fmaf(v, v, s);
    }
    enorm[e] = s;
}

// -------- prep A' v2: coalesced-in, LDS transpose, coalesced-out --------
// Ap layout: [mb 512][kc 8][m 128][64 shorts: slots swizzled (slot ^ (m&7))]
// split-K fragment: slot g shorts 0..3 = k g*4..+3, shorts 4..7 = 16+g*4..+3
__global__ __launch_bounds__(256) void prep_a(const float* __restrict__ x,
                                              short* __restrict__ Ap) {
    __shared__ short tile[8192];      // [m 128][64]
    const int tid = threadIdx.x;
    const int mb  = blockIdx.x;       // 0..511
    const int b   = mb >> 5;
    const int hw0 = (mb & 31) * 128;
    const float* xb = x + (((size_t)b * C_DIM) << 12) + hw0;

    for (int kc = 0; kc < 8; ++kc) {
        #pragma unroll
        for (int i = 0; i < 16; ++i) {
            int idx = i * 256 + tid;              // 0..4095
            int c32 = idx >> 7;                   // channel-in-kc 0..31
            int p   = idx & 127;                  // pixel-in-tile
            float v = xb[(((size_t)(kc * 32 + c32)) << 12) + p];
            u16 h = f2bf(v);
            u16 l = f2bf(v - bf2f(h));
            int cg3 = c32 >> 2, j = c32 & 3;
            int s = cg3 & 3, half = (cg3 >> 2) << 2;
            tile[p * 64 + (((s    ) ^ (p & 7)) << 3) + half + j] = (short)h;
            tile[p * 64 + (((s + 4) ^ (p & 7)) << 3) + half + j] = (short)l;
        }
        __syncthreads();
        short* dst = Ap + (size_t)mb * 65536 + kc * 8192;
        #pragma unroll
        for (int i = 0; i < 4; ++i) {
            int off = (i * 256 + tid) * 8;
            *(short8*)(dst + off) = *(const short8*)&tile[off];
        }
        __syncthreads();
    }
}

// -------- prep B': embed -> packed swizzled bf16 hi|lo tiles --------
// Bp layout: [nb 8][kc 8][e 128][64 shorts], same swizzle with (e&7)
__global__ __launch_bounds__(256) void prep_b(const float* __restrict__ embed,
                                              short* __restrict__ Bp) {
    int item = blockIdx.x * 256 + threadIdx.x;   // cg*1024 + e
    int e  = item & 1023;
    int cg = item >> 10;                         // 0..63
    const float* ep = embed + (size_t)(cg * 4) * N_EMB + e;
    float v0 = ep[0], v1 = ep[1024], v2 = ep[2048], v3 = ep[3072];
    u16 h0 = f2bf(v0), h1 = f2bf(v1), h2 = f2bf(v2), h3 = f2bf(v3);
    u16 l0 = f2bf(v0 - bf2f(h0)), l1 = f2bf(v1 - bf2f(h1));
    u16 l2 = f2bf(v2 - bf2f(h2)), l3 = f2bf(v3 - bf2f(h3));
    int eb = e & 127, nb = e >> 7;
    int kc = cg >> 3, cg3 = cg & 7;
    int s = cg3 & 3;
    int half = (cg3 >> 2) << 2;
    size_t row = (((size_t)(nb * 8 + kc)) * 128 + eb) * 64;
    int khi = ((s ^ (eb & 7)) << 3) + half;
    int klo = (((s + 4) ^ (eb & 7)) << 3) + half;
    *(u64*)(Bp + row + khi) = pack4(h0, h1, h2, h3);
    *(u64*)(Bp + row + klo) = pack4(l0, l1, l2, l3);
}

// -------- main MFMA distance GEMM: A-tile resident in LDS, B streamed --------
// 512 threads, 1 block/CU. A (128 KB) staged once; B (16 KB/step) reg-staged
// (T14 split: load at step top, ds_write after barrier). Running argmin in regs.
__global__ __launch_bounds__(512, 1) void vq_gemm(
    const short* __restrict__ Ap, const short* __restrict__ Bp,
    const float* __restrict__ enorm,
    int* __restrict__ ind, int* __restrict__ list, int* __restrict__ cnt)
{
    __shared__ __align__(1024) short As[65536];   // [kc 8][m 128][64]
    __shared__ __align__(1024) short Bs[8192];    // [e 128][64]
    __shared__ float eLDS[1024];
    __shared__ float mD[2][128];
    __shared__ float mS[2][128];
    __shared__ int   mI[2][128];

    const int tid  = threadIdx.x;
    const int mb   = blockIdx.x;      // 0..511
    const int wave = tid >> 6;        // 0..7
    const int lane = tid & 63;
    const int wm   = wave & 3;        // row-group: rows wm*32 + mi*16
    const int wn   = wave >> 2;       // col-group: cols wn*64 + ni*16
    const int col  = lane & 15;
    const int g    = lane >> 4;       // 0..3

    const short* Abase = Ap + (size_t)mb * 65536;

    // ---- prologue: A -> LDS (once), enorm -> LDS, B(0) -> regs -> LDS ----
    #pragma unroll
    for (int i = 0; i < 16; ++i) {
        int off = (i * 512 + tid) * 8;           // shorts
        GL2LDS(Abase + off, &As[off]);
    }
    eLDS[tid]       = enorm[tid];
    eLDS[tid + 512] = enorm[tid + 512];
    {
        const uint4* gb = (const uint4*)Bp;      // chunk t=0
        uint4 b0 = gb[tid];
        uint4 b1 = gb[512 + tid];
        *(uint4*)&Bs[tid * 8]         = b0;
        *(uint4*)&Bs[(512 + tid) * 8] = b1;
    }
    __syncthreads();    // drains gl2lds (vmcnt 0) + lgkm: As, Bs, eLDS ready

    // running per-thread (best, second, idx) for 8 rows (2 mi x 4 reg)
    float bd[2][4], sdv[2][4];
    int   bi[2][4];
    #pragma unroll
    for (int mi = 0; mi < 2; ++mi)
        #pragma unroll
        for (int reg = 0; reg < 4; ++reg) { bd[mi][reg] = FLT_MAX; sdv[mi][reg] = FLT_MAX; bi[mi][reg] = 0x7fffffff; }

    int t = 0;
    for (int nb = 0; nb < 8; ++nb) {
        f32x4 acc[2][4];
        #pragma unroll
        for (int mi = 0; mi < 2; ++mi)
            #pragma unroll
            for (int ni = 0; ni < 4; ++ni)
                acc[mi][ni] = (f32x4)0.0f;

        for (int kc = 0; kc < 8; ++kc, ++t) {
            const bool pf = (t < 63);
            uint4 p0, p1;
            if (pf) {   // prefetch B(t+1) into regs; latency hides under MFMA
                const uint4* gb = (const uint4*)(Bp + (size_t)(t + 1) * 8192);
                p0 = gb[tid];
                p1 = gb[512 + tid];
            }

            short8 ahi[2], alo[2], bhi[4], blo[4];
            #pragma unroll
            for (int mi = 0; mi < 2; ++mi) {
                int r = wm * 32 + mi * 16 + col;
                int base = kc * 8192 + r * 64;
                ahi[mi] = *(const short8*)&As[base + ((g ^ (r & 7)) << 3)];
                alo[mi] = *(const short8*)&As[base + (((g + 4) ^ (r & 7)) << 3)];
            }
            #pragma unroll
            for (int ni = 0; ni < 4; ++ni) {
                int r = wn * 64 + ni * 16 + col;
                int base = r * 64;
                bhi[ni] = *(const short8*)&Bs[base + ((g ^ (r & 7)) << 3)];
                blo[ni] = *(const short8*)&Bs[base + (((g + 4) ^ (r & 7)) << 3)];
            }
            #pragma unroll
            for (int mi = 0; mi < 2; ++mi)
                #pragma unroll
                for (int ni = 0; ni < 4; ++ni) {
                    acc[mi][ni] = __builtin_amdgcn_mfma_f32_16x16x32_bf16(ahi[mi], bhi[ni], acc[mi][ni], 0, 0, 0);
                    acc[mi][ni] = __builtin_amdgcn_mfma_f32_16x16x32_bf16(ahi[mi], blo[ni], acc[mi][ni], 0, 0, 0);
                    acc[mi][ni] = __builtin_amdgcn_mfma_f32_16x16x32_bf16(alo[mi], bhi[ni], acc[mi][ni], 0, 0, 0);
                }

            __syncthreads();            // all reads of Bs retired
            if (pf) {
                *(uint4*)&Bs[tid * 8]         = p0;   // compiler waits vmcnt here
                *(uint4*)&Bs[(512 + tid) * 8] = p1;
            }
            __syncthreads();            // Bs(t+1) ready
        }

        // fold this nb-chunk (code idx ascends over (nb,ni) -> strict <)
        float en[4];
        #pragma unroll
        for (int ni = 0; ni < 4; ++ni)
            en[ni] = eLDS[nb * 128 + wn * 64 + ni * 16 + col];
        #pragma unroll
        for (int mi = 0; mi < 2; ++mi)
            #pragma unroll
            for (int reg = 0; reg < 4; ++reg)
                #pragma unroll
                for (int ni = 0; ni < 4; ++ni) {
                    float d = en[ni] - 2.0f * acc[mi][ni][reg];
                    if (d < bd[mi][reg]) { sdv[mi][reg] = bd[mi][reg]; bd[mi][reg] = d; bi[mi][reg] = nb * 128 + wn * 64 + ni * 16 + col; }
                    else                 { sdv[mi][reg] = fminf(sdv[mi][reg], d); }
                }
    }

    // cross-col shfl reduce, then cross-wn LDS merge
    #pragma unroll
    for (int mi = 0; mi < 2; ++mi) {
        #pragma unroll
        for (int reg = 0; reg < 4; ++reg) {
            float b = bd[mi][reg], s2 = sdv[mi][reg];
            int   i2 = bi[mi][reg];
            #pragma unroll
            for (int mask = 1; mask < 16; mask <<= 1) {
                float ob = __shfl_xor(b, mask);
                float os = __shfl_xor(s2, mask);
                int   oi = __shfl_xor(i2, mask);
                if (ob < b || (ob == b && oi < i2)) { s2 = fminf(b, os); b = ob; i2 = oi; }
                else                                { s2 = fminf(s2, ob); }
            }
            if (col == 0) {
                int pl = wm * 32 + mi * 16 + g * 4 + reg;   // 0..127
                mD[wn][pl] = b; mS[wn][pl] = s2; mI[wn][pl] = i2;
            }
        }
    }
    __syncthreads();
    if (tid < 128) {
        float b0 = mD[0][tid], s0 = mS[0][tid];
        int   i0 = mI[0][tid];
        float b1 = mD[1][tid], s1 = mS[1][tid];
        int   i1 = mI[1][tid];
        float b, s; int i;
        if (b1 < b0 || (b1 == b0 && i1 < i0)) { b = b1; i = i1; s = fminf(b0, s1); }
        else                                  { b = b0; i = i0; s = fminf(s0, b1); }
        int p = mb * 128 + tid;
        ind[p] = i;
        if (s - b < TAU) {
            int pos = atomicAdd(cnt, 1);
            list[pos] = p;
        }
    }
}

// -------- exact f32 re-check for ambiguous pixels (round-1 numerics) --------
__global__ __launch_bounds__(256) void vq_fixup(
    const float* __restrict__ x, const float* __restrict__ embed,
    const float* __restrict__ enorm, const int* __restrict__ list,
    const int* __restrict__ cnt, int* __restrict__ ind)
{
    __shared__ float xr[256];
    __shared__ float xnsh;
    __shared__ float rD[256];
    __shared__ int   rI[256];
    const int tid = threadIdx.x;
    const int nfix = cnt[0];

    for (int j = blockIdx.x; j < nfix; j += gridDim.x) {
        int p = list[j];
        int b = p >> 12, hw = p & 4095;
        xr[tid] = x[(((size_t)(b * C_DIM + tid)) << 12) + hw];
        __syncthreads();
        if (tid == 0) {
            float s = 0.f;
            for (int c = 0; c < C_DIM; ++c) s = fmaf(xr[c], xr[c], s);
            xnsh = s;
        }
        __syncthreads();
        float xn = xnsh;
        float best = FLT_MAX; int bidx = 0;
        #pragma unroll
        for (int j4 = 0; j4 < 4; ++j4) {
            int e = j4 * 256 + tid;
            float acc = 0.f;
            for (int c = 0; c < C_DIM; ++c) acc = fmaf(xr[c], embed[c * N_EMB + e], acc);
            float d = (xn - 2.0f * acc) + enorm[e];
            if (d < best) { best = d; bidx = e; }
        }
        rD[tid] = best; rI[tid] = bidx;
        __syncthreads();
        for (int st = 128; st > 0; st >>= 1) {
            if (tid < st) {
                float od = rD[tid + st]; int oi = rI[tid + st];
                if (od < rD[tid] || (od == rD[tid] && oi < rI[tid])) { rD[tid] = od; rI[tid] = oi; }
            }
            __syncthreads();
        }
        if (tid == 0) ind[p] = rI[0];
        __syncthreads();
    }
}

// -------- final: quantize gather + embed_ind + diff partials --------
__global__ __launch_bounds__(256) void vq_final(
    const float* __restrict__ x, const float* __restrict__ embed,
    const int* __restrict__ ind, float* __restrict__ out,
    float* __restrict__ diff_partial)
{
    __shared__ int bl[64];
    __shared__ float wsum[4];
    const int tid = threadIdx.x;
    const int bid = blockIdx.x;      // (b,h) row: 64 pixels
    const int b = bid >> 6;
    if (tid < 64) {
        int e = ind[bid * 64 + tid];
        bl[tid] = e;
        out[(size_t)QN + 1 + (size_t)bid * 64 + tid] = (float)e;
    }
    __syncthreads();
    const int h = bid & 63;
    float local = 0.f;
    for (int it = 0; it < 64; ++it) {
        int i = it * 256 + tid;
        int c = i >> 6, w = i & 63;
        int e = bl[w];
        float q = embed[c * N_EMB + e];
        size_t o = (((size_t)(b * C_DIM + c)) << 12) + h * 64 + w;
        out[o] = q;
        float dv = q - x[o];
        local = fmaf(dv, dv, local);
    }
    #pragma unroll
    for (int off = 32; off > 0; off >>= 1) local += __shfl_down(local, off);
    if ((tid & 63) == 0) wsum[tid >> 6] = local;
    __syncthreads();
    if (tid == 0) diff_partial[bid] = wsum[0] + wsum[1] + wsum[2] + wsum[3];
}

// -------- finalize diff in f64 --------
__global__ __launch_bounds__(256) void finalize_kernel(const float* __restrict__ part,
                                                       float* __restrict__ out) {
    __shared__ double sd_[256];
    double s = 0.0;
    for (int i = threadIdx.x; i < 1024; i += 256) s += (double)part[i];
    sd_[threadIdx.x] = s;
    __syncthreads();
    for (int st = 128; st > 0; st >>= 1) {
        if (threadIdx.x < st) sd_[threadIdx.x] += sd_[threadIdx.x + st];
        __syncthreads();
    }
    if (threadIdx.x == 0) out[QN] = (float)(sd_[0] / 16777216.0);
}

// ================== round-1 fallback (small ws) ==================
__global__ __launch_bounds__(256) void vq_main_fb(
    const float* __restrict__ x, const float* __restrict__ embed,
    const float* __restrict__ enorm, float* __restrict__ out,
    float* __restrict__ diff_partial)
{
    __shared__ float xs[C_DIM][64];
    __shared__ float es[32 * 128];
    const int tid = threadIdx.x;
    const int bid = blockIdx.x;
    const int b = bid >> 6;
    const int h = bid & 63;
    const float* xb = x + (size_t)(b * C_DIM) * HW + h * 64;
    for (int i = tid; i < C_DIM * 64; i += 256)
        ((float*)xs)[i] = xb[(i >> 6) * HW + (i & 63)];
    __syncthreads();
    const int tp = tid & 15;
    const int te = tid >> 4;
    float xn[4];
    #pragma unroll
    for (int pi = 0; pi < 4; ++pi) {
        int p = tp * 4 + pi;
        float s = 0.f;
        for (int c = 0; c < C_DIM; ++c) s = fmaf(xs[c][p], xs[c][p], s);
        xn[pi] = s;
    }
    float bestd[4]; int besti[4];
    #pragma unroll
    for (int pi = 0; pi < 4; ++pi) { bestd[pi] = 3.0e38f; besti[pi] = 0; }
    for (int ec = 0; ec < 8; ++ec) {
        float acc[4][8];
        #pragma unroll
        for (int pi = 0; pi < 4; ++pi)
            #pragma unroll
            for (int j = 0; j < 8; ++j) acc[pi][j] = 0.f;
        for (int kc = 0; kc < 8; ++kc) {
            __syncthreads();
            for (int i = tid; i < 32 * 128; i += 256) {
                int k = i >> 7, e = i & 127;
                es[i] = embed[(size_t)(kc * 32 + k) * N_EMB + ec * 128 + e];
            }
            __syncthreads();
            #pragma unroll
            for (int k = 0; k < 32; ++k) {
                float4 xv = *(const float4*)&xs[kc * 32 + k][tp * 4];
                float ev[8];
                *(float4*)&ev[0] = *(const float4*)&es[k * 128 + te * 8];
                *(float4*)&ev[4] = *(const float4*)&es[k * 128 + te * 8 + 4];
                #pragma unroll
                for (int pi = 0; pi < 4; ++pi) {
                    float xvv = (&xv.x)[pi];
                    #pragma unroll
                    for (int j = 0; j < 8; ++j)
                        acc[pi][j] = fmaf(xvv, ev[j], acc[pi][j]);
                }
            }
        }
        #pragma unroll
        for (int pi = 0; pi < 4; ++pi)
            #pragma unroll
            for (int j = 0; j < 8; ++j) {
                int e = ec * 128 + te * 8 + j;
                float d = (xn[pi] - 2.0f * acc[pi][j]) + enorm[e];
                if (d < bestd[pi]) { bestd[pi] = d; besti[pi] = e; }
            }
    }
    float* redD = es;
    int*   redI = (int*)(es + 1024);
    int*   best = (int*)(es + 2048);
    float* wsum = es + 3072;
    __syncthreads();
    #pragma unroll
    for (int pi = 0; pi < 4; ++pi) {
        int p = tp * 4 + pi;
        redD[te * 64 + p] = bestd[pi];
        redI[te * 64 + p] = besti[pi];
    }
    __syncthreads();
    if (tid < 64) {
        int p = tid;
        float bdv = redD[p]; int biv = redI[p];
        #pragma unroll
        for (int gg = 1; gg < 16; ++gg) {
            float d = redD[gg * 64 + p]; int i2 = redI[gg * 64 + p];
            if (d < bdv || (d == bdv && i2 < biv)) { bdv = d; biv = i2; }
        }
        best[p] = biv;
        out[(size_t)QN + 1 + (size_t)bid * 64 + p] = (float)biv;
    }
    __syncthreads();
    float local = 0.f;
    for (int i = tid; i < C_DIM * 64; i += 256) {
        int c = i >> 6, w = i & 63;
        int e = best[w];
        float q = embed[c * N_EMB + e];
        out[(size_t)(b * C_DIM + c) * HW + h * 64 + w] = q;
        float dv = q - xs[c][w];
        local = fmaf(dv, dv, local);
    }
    #pragma unroll
    for (int off = 32; off > 0; off >>= 1) local += __shfl_down(local, off);
    if ((tid & 63) == 0) wsum[tid >> 6] = local;
    __syncthreads();
    if (tid == 0) diff_partial[bid] = wsum[0] + wsum[1] + wsum[2] + wsum[3];
}

extern "C" void kernel_launch(void* const* d_in, const int* in_sizes, int n_in,
                              void* d_out, int out_size, void* d_ws, size_t ws_size,
                              hipStream_t stream) {
    const float* x     = (const float*)d_in[0];
    const float* embed = (const float*)d_in[1];
    float* out = (float*)d_out;
    char*  ws  = (char*)d_ws;

    if (ws_size >= 70ull * 1048576ull) {
        short* Ap    = (short*)(ws);                     // 64 MB
        short* Bp    = (short*)(ws + (64ull << 20));     // 1 MB
        float* enorm = (float*)(ws + (65ull << 20));     // 4 KB
        int*   ind   = (int*)  (ws + (66ull << 20));     // 256 KB
        int*   list  = (int*)  (ws + (67ull << 20));     // 256 KB
        int*   cnt   = (int*)  (ws + (68ull << 20));     // 4 B
        float* part  = (float*)(ws + (68ull << 20) + 4096);

        enorm_kernel<<<4, 256, 0, stream>>>(embed, enorm, cnt);
        prep_a<<<512, 256, 0, stream>>>(x, Ap);
        prep_b<<<256, 256, 0, stream>>>(embed, Bp);
        vq_gemm<<<512, 512, 0, stream>>>(Ap, Bp, enorm, ind, list, cnt);
        vq_fixup<<<1024, 256, 0, stream>>>(x, embed, enorm, list, cnt, ind);
        vq_final<<<1024, 256, 0, stream>>>(x, embed, ind, out, part);
        finalize_kernel<<<1, 256, 0, stream>>>(part, out);
    } else {
        float* enorm = (float*)ws;
        float* part  = enorm + 1024;
        enorm_kernel<<<4, 256, 0, stream>>>(embed, enorm, (int*)(enorm + 2048));
        vq_main_fb<<<1024, 256, 0, stream>>>(x, embed, enorm, out, part);
        finalize_kernel<<<1, 256, 0, stream>>>(part, out);
    }
}

// Round 8
// 196.307 us; speedup vs baseline: 4.6195x; 1.2252x over previous
//
#include <hip/hip_runtime.h>
#include <float.h>

#define C_DIM 256
#define N_EMB 1024
#define HW    4096          // 64*64
#define QN    16777216      // quantize element count
#define NPIX  65536
#define TAU   4.0e-3f

typedef __attribute__((ext_vector_type(8))) short short8;
typedef __attribute__((ext_vector_type(4))) float f32x4;
typedef unsigned long long u64;
typedef unsigned int u32;
typedef unsigned short u16;

__device__ __forceinline__ u16 f2bf(float f) {
    u32 u = __float_as_uint(f);
    return (u16)((u + 0x7FFF + ((u >> 16) & 1)) >> 16);   // RN-even, inputs finite
}
__device__ __forceinline__ float bf2f(u16 h) { return __uint_as_float(((u32)h) << 16); }
__device__ __forceinline__ u64 pack4(u16 a, u16 b, u16 c, u16 d) {
    return (u64)a | ((u64)b << 16) | ((u64)c << 32) | ((u64)d << 48);
}

// -------- kernel: ||e||^2 per code (+ zero the fixup counter) --------
__global__ __launch_bounds__(256) void enorm_kernel(const float* __restrict__ embed,
                                                    float* __restrict__ enorm,
                                                    int* __restrict__ cnt) {
    if (blockIdx.x == 0 && threadIdx.x == 0) cnt[0] = 0;
    int e = blockIdx.x * 256 + threadIdx.x;
    float s = 0.f;
    #pragma unroll 8
    for (int c = 0; c < C_DIM; ++c) {
        float v = embed[c * N_EMB + e];
        s = fmaf(v, v, s);
    }
    enorm[e] = s;
}

// -------- prep B': embed -> packed swizzled bf16 hi|lo tiles --------
// Bp layout: [nb 8][kc 8][e 128][64 shorts], slot swizzle (slot ^ (e&7))
// split-K fragment: slot g shorts 0..3 = k g*4..+3, shorts 4..7 = 16+g*4..+3
__global__ __launch_bounds__(256) void prep_b(const float* __restrict__ embed,
                                              short* __restrict__ Bp) {
    int item = blockIdx.x * 256 + threadIdx.x;   // cg*1024 + e
    int e  = item & 1023;
    int cg = item >> 10;                         // 0..63
    const float* ep = embed + (size_t)(cg * 4) * N_EMB + e;
    float v0 = ep[0], v1 = ep[1024], v2 = ep[2048], v3 = ep[3072];
    u16 h0 = f2bf(v0), h1 = f2bf(v1), h2 = f2bf(v2), h3 = f2bf(v3);
    u16 l0 = f2bf(v0 - bf2f(h0)), l1 = f2bf(v1 - bf2f(h1));
    u16 l2 = f2bf(v2 - bf2f(h2)), l3 = f2bf(v3 - bf2f(h3));
    int eb = e & 127, nb = e >> 7;
    int kc = cg >> 3, cg3 = cg & 7;
    int s = cg3 & 3;
    int half = (cg3 >> 2) << 2;
    size_t row = (((size_t)(nb * 8 + kc)) * 128 + eb) * 64;
    int khi = ((s ^ (eb & 7)) << 3) + half;
    int klo = (((s + 4) ^ (eb & 7)) << 3) + half;
    *(u64*)(Bp + row + khi) = pack4(h0, h1, h2, h3);
    *(u64*)(Bp + row + klo) = pack4(l0, l1, l2, l3);
}

// -------- main MFMA distance GEMM: fused A-convert, A-resident, B dbuf --------
// 512 threads, 1 block/CU (160 KB LDS). A staged+converted once from x (f32);
// B streamed double-buffered (reg prefetch -> ds_write to buf^1), ONE barrier
// per step; setprio around MFMA cluster. Running argmin in registers.
__global__ __launch_bounds__(512, 1) void vq_gemm(
    const float* __restrict__ x, const short* __restrict__ Bp,
    const float* __restrict__ enorm,
    int* __restrict__ ind, int* __restrict__ list, int* __restrict__ cnt)
{
    __shared__ __align__(1024) short As[65536];    // [kc 8][p 128][64]   128 KB
    __shared__ __align__(1024) short Bs[2][8192];  // [buf][e 128][64]     32 KB

    const int tid  = threadIdx.x;
    const int mb   = blockIdx.x;      // 0..511
    const int wave = tid >> 6;        // 0..7
    const int lane = tid & 63;
    const int wm   = wave & 3;        // row-group: rows wm*32 + mi*16
    const int wn   = wave >> 2;       // col-group: cols wn*64 + ni*16
    const int col  = lane & 15;
    const int g    = lane >> 4;       // 0..3

    // ---- fused A staging: x (f32, coalesced) -> convert -> swizzled As ----
    {
        const int b   = mb >> 5;
        const int hw0 = (mb & 31) * 128;
        const float* xb = x + (((size_t)b * C_DIM) << 12) + hw0;
        float* scratch = (float*)Bs;   // 16 KB scratch, [c32 32][p 128]

        for (int kc = 0; kc < 8; ++kc) {
            {
                int c32 = tid >> 4, p = (tid & 15) * 8;
                const float* sp = xb + (((size_t)(kc * 32 + c32)) << 12) + p;
                float4 v0 = *(const float4*)sp;
                float4 v1 = *(const float4*)(sp + 4);
                ((float4*)scratch)[tid * 2]     = v0;   // == scratch[c32*128+p]
                ((float4*)scratch)[tid * 2 + 1] = v1;
            }
            __syncthreads();
            #pragma unroll
            for (int it = 0; it < 2; ++it) {
                int item = it * 512 + tid;        // cg8*128 + p
                int cg8 = item >> 7, p = item & 127;
                float v0 = scratch[(cg8 * 4 + 0) * 128 + p];
                float v1 = scratch[(cg8 * 4 + 1) * 128 + p];
                float v2 = scratch[(cg8 * 4 + 2) * 128 + p];
                float v3 = scratch[(cg8 * 4 + 3) * 128 + p];
                u16 h0 = f2bf(v0), h1 = f2bf(v1), h2 = f2bf(v2), h3 = f2bf(v3);
                u16 l0 = f2bf(v0 - bf2f(h0)), l1 = f2bf(v1 - bf2f(h1));
                u16 l2 = f2bf(v2 - bf2f(h2)), l3 = f2bf(v3 - bf2f(h3));
                int s = cg8 & 3, half = (cg8 >> 2) << 2;
                short* rowp = As + kc * 8192 + p * 64;
                *(u64*)(rowp + ((s ^ (p & 7)) << 3) + half)       = pack4(h0, h1, h2, h3);
                *(u64*)(rowp + (((s + 4) ^ (p & 7)) << 3) + half) = pack4(l0, l1, l2, l3);
            }
            __syncthreads();
        }
    }

    // ---- B(0) -> Bs[0] ----
    {
        const uint4* gb = (const uint4*)Bp;
        uint4 b0 = gb[tid];
        uint4 b1 = gb[512 + tid];
        *(uint4*)&Bs[0][tid * 8]         = b0;
        *(uint4*)&Bs[0][(512 + tid) * 8] = b1;
    }
    __syncthreads();

    // running per-thread (best, second, idx) for 8 rows (2 mi x 4 reg)
    float bd[2][4], sdv[2][4];
    int   bi[2][4];
    #pragma unroll
    for (int mi = 0; mi < 2; ++mi)
        #pragma unroll
        for (int reg = 0; reg < 4; ++reg) { bd[mi][reg] = FLT_MAX; sdv[mi][reg] = FLT_MAX; bi[mi][reg] = 0x7fffffff; }

    int cur = 0;
    int t = 0;
    for (int nb = 0; nb < 8; ++nb) {
        float en[4];
        #pragma unroll
        for (int ni = 0; ni < 4; ++ni)
            en[ni] = enorm[nb * 128 + wn * 64 + ni * 16 + col];   // L2-hot

        f32x4 acc[2][4];
        #pragma unroll
        for (int mi = 0; mi < 2; ++mi)
            #pragma unroll
            for (int ni = 0; ni < 4; ++ni)
                acc[mi][ni] = (f32x4)0.0f;

        for (int kc = 0; kc < 8; ++kc, ++t) {
            const bool pf = (t < 63);
            uint4 p0, p1;
            if (pf) {   // prefetch B(t+1) into regs; consumed by ds_write below
                const uint4* gb = (const uint4*)(Bp + (size_t)(t + 1) * 8192);
                p0 = gb[tid];
                p1 = gb[512 + tid];
            }

            short8 ahi[2], alo[2], bhi[4], blo[4];
            #pragma unroll
            for (int mi = 0; mi < 2; ++mi) {
                int r = wm * 32 + mi * 16 + col;
                int base = kc * 8192 + r * 64;
                ahi[mi] = *(const short8*)&As[base + ((g ^ (r & 7)) << 3)];
                alo[mi] = *(const short8*)&As[base + (((g + 4) ^ (r & 7)) << 3)];
            }
            #pragma unroll
            for (int ni = 0; ni < 4; ++ni) {
                int r = wn * 64 + ni * 16 + col;
                int base = r * 64;
                bhi[ni] = *(const short8*)&Bs[cur][base + ((g ^ (r & 7)) << 3)];
                blo[ni] = *(const short8*)&Bs[cur][base + (((g + 4) ^ (r & 7)) << 3)];
            }
            __builtin_amdgcn_s_setprio(1);
            #pragma unroll
            for (int mi = 0; mi < 2; ++mi)
                #pragma unroll
                for (int ni = 0; ni < 4; ++ni) {
                    acc[mi][ni] = __builtin_amdgcn_mfma_f32_16x16x32_bf16(ahi[mi], bhi[ni], acc[mi][ni], 0, 0, 0);
                    acc[mi][ni] = __builtin_amdgcn_mfma_f32_16x16x32_bf16(ahi[mi], blo[ni], acc[mi][ni], 0, 0, 0);
                    acc[mi][ni] = __builtin_amdgcn_mfma_f32_16x16x32_bf16(alo[mi], bhi[ni], acc[mi][ni], 0, 0, 0);
                }
            __builtin_amdgcn_s_setprio(0);

            if (pf) {   // write into the *other* buffer: no reader this step
                *(uint4*)&Bs[cur ^ 1][tid * 8]         = p0;
                *(uint4*)&Bs[cur ^ 1][(512 + tid) * 8] = p1;
            }
            __syncthreads();   // prev writes visible + this step's reads retired
            cur ^= 1;
        }

        // fold this nb-chunk (code idx ascends over (nb,ni) -> strict <)
        #pragma unroll
        for (int mi = 0; mi < 2; ++mi)
            #pragma unroll
            for (int reg = 0; reg < 4; ++reg)
                #pragma unroll
                for (int ni = 0; ni < 4; ++ni) {
                    float d = en[ni] - 2.0f * acc[mi][ni][reg];
                    if (d < bd[mi][reg]) { sdv[mi][reg] = bd[mi][reg]; bd[mi][reg] = d; bi[mi][reg] = nb * 128 + wn * 64 + ni * 16 + col; }
                    else                 { sdv[mi][reg] = fminf(sdv[mi][reg], d); }
                }
    }

    // epilogue merge: alias Bs (all tile reads retired at last barrier)
    float* mD = (float*)Bs;            // [2][128]
    float* mS = mD + 256;              // [2][128]
    int*   mI = (int*)(mS + 256);      // [2][128]

    #pragma unroll
    for (int mi = 0; mi < 2; ++mi) {
        #pragma unroll
        for (int reg = 0; reg < 4; ++reg) {
            float b = bd[mi][reg], s2 = sdv[mi][reg];
            int   i2 = bi[mi][reg];
            #pragma unroll
            for (int mask = 1; mask < 16; mask <<= 1) {
                float ob = __shfl_xor(b, mask);
                float os = __shfl_xor(s2, mask);
                int   oi = __shfl_xor(i2, mask);
                if (ob < b || (ob == b && oi < i2)) { s2 = fminf(b, os); b = ob; i2 = oi; }
                else                                { s2 = fminf(s2, ob); }
            }
            if (col == 0) {
                int pl = wm * 32 + mi * 16 + g * 4 + reg;   // 0..127
                mD[wn * 128 + pl] = b; mS[wn * 128 + pl] = s2; mI[wn * 128 + pl] = i2;
            }
        }
    }
    __syncthreads();
    if (tid < 128) {
        float b0 = mD[tid],      s0 = mS[tid];
        int   i0 = mI[tid];
        float b1 = mD[128 + tid], s1 = mS[128 + tid];
        int   i1 = mI[128 + tid];
        float b, s; int i;
        if (b1 < b0 || (b1 == b0 && i1 < i0)) { b = b1; i = i1; s = fminf(b0, s1); }
        else                                  { b = b0; i = i0; s = fminf(s0, b1); }
        int p = mb * 128 + tid;
        ind[p] = i;
        if (s - b < TAU) {
            int pos = atomicAdd(cnt, 1);
            list[pos] = p;
        }
    }
}

// -------- exact f32 re-check for ambiguous pixels (round-1 numerics) --------
__global__ __launch_bounds__(256) void vq_fixup(
    const float* __restrict__ x, const float* __restrict__ embed,
    const float* __restrict__ enorm, const int* __restrict__ list,
    const int* __restrict__ cnt, int* __restrict__ ind)
{
    __shared__ float xr[256];
    __shared__ float xnsh;
    __shared__ float rD[256];
    __shared__ int   rI[256];
    const int tid = threadIdx.x;
    const int nfix = cnt[0];

    for (int j = blockIdx.x; j < nfix; j += gridDim.x) {
        int p = list[j];
        int b = p >> 12, hw = p & 4095;
        xr[tid] = x[(((size_t)(b * C_DIM + tid)) << 12) + hw];
        __syncthreads();
        if (tid == 0) {
            float s = 0.f;
            for (int c = 0; c < C_DIM; ++c) s = fmaf(xr[c], xr[c], s);
            xnsh = s;
        }
        __syncthreads();
        float xn = xnsh;
        float best = FLT_MAX; int bidx = 0;
        #pragma unroll
        for (int j4 = 0; j4 < 4; ++j4) {
            int e = j4 * 256 + tid;
            float acc = 0.f;
            for (int c = 0; c < C_DIM; ++c) acc = fmaf(xr[c], embed[c * N_EMB + e], acc);
            float d = (xn - 2.0f * acc) + enorm[e];
            if (d < best) { best = d; bidx = e; }
        }
        rD[tid] = best; rI[tid] = bidx;
        __syncthreads();
        for (int st = 128; st > 0; st >>= 1) {
            if (tid < st) {
                float od = rD[tid + st]; int oi = rI[tid + st];
                if (od < rD[tid] || (od == rD[tid] && oi < rI[tid])) { rD[tid] = od; rI[tid] = oi; }
            }
            __syncthreads();
        }
        if (tid == 0) ind[p] = rI[0];
        __syncthreads();
    }
}

// -------- final: quantize gather + embed_ind + diff partials --------
__global__ __launch_bounds__(256) void vq_final(
    const float* __restrict__ x, const float* __restrict__ embed,
    const int* __restrict__ ind, float* __restrict__ out,
    float* __restrict__ diff_partial)
{
    __shared__ int bl[64];
    __shared__ float wsum[4];
    const int tid = threadIdx.x;
    const int bid = blockIdx.x;      // (b,h) row: 64 pixels
    const int b = bid >> 6;
    if (tid < 64) {
        int e = ind[bid * 64 + tid];
        bl[tid] = e;
        out[(size_t)QN + 1 + (size_t)bid * 64 + tid] = (float)e;
    }
    __syncthreads();
    const int h = bid & 63;
    float local = 0.f;
    for (int it = 0; it < 64; ++it) {
        int i = it * 256 + tid;
        int c = i >> 6, w = i & 63;
        int e = bl[w];
        float q = embed[c * N_EMB + e];
        size_t o = (((size_t)(b * C_DIM + c)) << 12) + h * 64 + w;
        out[o] = q;
        float dv = q - x[o];
        local = fmaf(dv, dv, local);
    }
    #pragma unroll
    for (int off = 32; off > 0; off >>= 1) local += __shfl_down(local, off);
    if ((tid & 63) == 0) wsum[tid >> 6] = local;
    __syncthreads();
    if (tid == 0) diff_partial[bid] = wsum[0] + wsum[1] + wsum[2] + wsum[3];
}

// -------- finalize diff in f64 --------
__global__ __launch_bounds__(256) void finalize_kernel(const float* __restrict__ part,
                                                       float* __restrict__ out) {
    __shared__ double sd_[256];
    double s = 0.0;
    for (int i = threadIdx.x; i < 1024; i += 256) s += (double)part[i];
    sd_[threadIdx.x] = s;
    __syncthreads();
    for (int st = 128; st > 0; st >>= 1) {
        if (threadIdx.x < st) sd_[threadIdx.x] += sd_[threadIdx.x + st];
        __syncthreads();
    }
    if (threadIdx.x == 0) out[QN] = (float)(sd_[0] / 16777216.0);
}

// ================== round-1 fallback (small ws) ==================
__global__ __launch_bounds__(256) void vq_main_fb(
    const float* __restrict__ x, const float* __restrict__ embed,
    const float* __restrict__ enorm, float* __restrict__ out,
    float* __restrict__ diff_partial)
{
    __shared__ float xs[C_DIM][64];
    __shared__ float es[32 * 128];
    const int tid = threadIdx.x;
    const int bid = blockIdx.x;
    const int b = bid >> 6;
    const int h = bid & 63;
    const float* xb = x + (size_t)(b * C_DIM) * HW + h * 64;
    for (int i = tid; i < C_DIM * 64; i += 256)
        ((float*)xs)[i] = xb[(i >> 6) * HW + (i & 63)];
    __syncthreads();
    const int tp = tid & 15;
    const int te = tid >> 4;
    float xn[4];
    #pragma unroll
    for (int pi = 0; pi < 4; ++pi) {
        int p = tp * 4 + pi;
        float s = 0.f;
        for (int c = 0; c < C_DIM; ++c) s = fmaf(xs[c][p], xs[c][p], s);
        xn[pi] = s;
    }
    float bestd[4]; int besti[4];
    #pragma unroll
    for (int pi = 0; pi < 4; ++pi) { bestd[pi] = 3.0e38f; besti[pi] = 0; }
    for (int ec = 0; ec < 8; ++ec) {
        float acc[4][8];
        #pragma unroll
        for (int pi = 0; pi < 4; ++pi)
            #pragma unroll
            for (int j = 0; j < 8; ++j) acc[pi][j] = 0.f;
        for (int kc = 0; kc < 8; ++kc) {
            __syncthreads();
            for (int i = tid; i < 32 * 128; i += 256) {
                int k = i >> 7, e = i & 127;
                es[i] = embed[(size_t)(kc * 32 + k) * N_EMB + ec * 128 + e];
            }
            __syncthreads();
            #pragma unroll
            for (int k = 0; k < 32; ++k) {
                float4 xv = *(const float4*)&xs[kc * 32 + k][tp * 4];
                float ev[8];
                *(float4*)&ev[0] = *(const float4*)&es[k * 128 + te * 8];
                *(float4*)&ev[4] = *(const float4*)&es[k * 128 + te * 8 + 4];
                #pragma unroll
                for (int pi = 0; pi < 4; ++pi) {
                    float xvv = (&xv.x)[pi];
                    #pragma unroll
                    for (int j = 0; j < 8; ++j)
                        acc[pi][j] = fmaf(xvv, ev[j], acc[pi][j]);
                }
            }
        }
        #pragma unroll
        for (int pi = 0; pi < 4; ++pi)
            #pragma unroll
            for (int j = 0; j < 8; ++j) {
                int e = ec * 128 + te * 8 + j;
                float d = (xn[pi] - 2.0f * acc[pi][j]) + enorm[e];
                if (d < bestd[pi]) { bestd[pi] = d; besti[pi] = e; }
            }
    }
    float* redD = es;
    int*   redI = (int*)(es + 1024);
    int*   best = (int*)(es + 2048);
    float* wsum = es + 3072;
    __syncthreads();
    #pragma unroll
    for (int pi = 0; pi < 4; ++pi) {
        int p = tp * 4 + pi;
        redD[te * 64 + p] = bestd[pi];
        redI[te * 64 + p] = besti[pi];
    }
    __syncthreads();
    if (tid < 64) {
        int p = tid;
        float bdv = redD[p]; int biv = redI[p];
        #pragma unroll
        for (int gg = 1; gg < 16; ++gg) {
            float d = redD[gg * 64 + p]; int i2 = redI[gg * 64 + p];
            if (d < bdv || (d == bdv && i2 < biv)) { bdv = d; biv = i2; }
        }
        best[p] = biv;
        out[(size_t)QN + 1 + (size_t)bid * 64 + p] = (float)biv;
    }
    __syncthreads();
    float local = 0.f;
    for (int i = tid; i < C_DIM * 64; i += 256) {
        int c = i >> 6, w = i & 63;
        int e = best[w];
        float q = embed[c * N_EMB + e];
        out[(size_t)(b * C_DIM + c) * HW + h * 64 + w] = q;
        float dv = q - xs[c][w];
        local = fmaf(dv, dv, local);
    }
    #pragma unroll
    for (int off = 32; off > 0; off >>= 1) local += __shfl_down(local, off);
    if ((tid & 63) == 0) wsum[tid >> 6] = local;
    __syncthreads();
    if (tid == 0) diff_partial[bid] = wsum[0] + wsum[1] + wsum[2] + wsum[3];
}

extern "C" void kernel_launch(void* const* d_in, const int* in_sizes, int n_in,
                              void* d_out, int out_size, void* d_ws, size_t ws_size,
                              hipStream_t stream) {
    const float* x     = (const float*)d_in[0];
    const float* embed = (const float*)d_in[1];
    float* out = (float*)d_out;
    char*  ws  = (char*)d_ws;

    if (ws_size >= 8ull * 1048576ull) {
        short* Bp    = (short*)(ws);                    // 1 MB
        float* enorm = (float*)(ws + (1ull << 20));     // 4 KB
        int*   ind   = (int*)  (ws + (2ull << 20));     // 256 KB
        int*   list  = (int*)  (ws + (3ull << 20));     // 256 KB
        int*   cnt   = (int*)  (ws + (4ull << 20));     // 4 B
        float* part  = (float*)(ws + (4ull << 20) + 4096);

        enorm_kernel<<<4, 256, 0, stream>>>(embed, enorm, cnt);
        prep_b<<<256, 256, 0, stream>>>(embed, Bp);
        vq_gemm<<<512, 512, 0, stream>>>(x, Bp, enorm, ind, list, cnt);
        vq_fixup<<<1024, 256, 0, stream>>>(x, embed, enorm, list, cnt, ind);
        vq_final<<<1024, 256, 0, stream>>>(x, embed, ind, out, part);
        finalize_kernel<<<1, 256, 0, stream>>>(part, out);
    } else {
        float* enorm = (float*)ws;
        float* part  = enorm + 1024;
        enorm_kernel<<<4, 256, 0, stream>>>(embed, enorm, (int*)(enorm + 2048));
        vq_main_fb<<<1024, 256, 0, stream>>>(x, embed, enorm, out, part);
        finalize_kernel<<<1, 256, 0, stream>>>(part, out);
    }
}